// Round 1
// baseline (348.256 us; speedup 1.0000x reference)
//
#include <hip/hip_runtime.h>
#include <hip/hip_bf16.h>

// ---------------------------------------------------------------------------
// Problem constants (BATCH=1)
#define SEQ    2048
#define DM     2048
#define NH     16
#define DH     128
#define EPS    1e-5f
#define SCALE_INV 0.08838834764831845f   // 1/sqrt(128)

typedef unsigned short u16;
typedef u16  u16x4  __attribute__((ext_vector_type(4)));
typedef u16  u16x8  __attribute__((ext_vector_type(8)));
typedef __bf16 bf16x8 __attribute__((ext_vector_type(8)));
typedef float f32x4 __attribute__((ext_vector_type(4)));

__device__ __forceinline__ u16 f2bf(float f) {
    unsigned int u = __builtin_bit_cast(unsigned int, f);
    u += 0x7fffu + ((u >> 16) & 1u);      // RNE
    return (u16)(u >> 16);
}
__device__ __forceinline__ bf16x8 as_bf(u16x8 v) { return __builtin_bit_cast(bf16x8, v); }

// ---------------------------------------------------------------------------
// 1) rotary table: tab[pos][i] = {sin(pos/10000^(i/64)), cos(...)}, i=0..63
__global__ void rope_kernel(float2* __restrict__ tab) {
    int i = threadIdx.x;                 // 0..63
    int pos = blockIdx.x;                // 0..2047
    float freq = powf(10000.f, (float)i * (1.f / 64.f));
    float ang = (float)pos / freq;
    tab[pos * 64 + i] = make_float2(sinf(ang), cosf(ang));
}

// ---------------------------------------------------------------------------
// 2) LayerNorm (center + rms of centered) fp32 -> bf16
__global__ __launch_bounds__(256) void ln_kernel(const float* __restrict__ x,
                                                 u16* __restrict__ xn) {
    int row = blockIdx.x, t = threadIdx.x;
    const float* xr = x + (size_t)row * DM;
    float4 v0 = *(const float4*)(xr + t * 4);
    float4 v1 = *(const float4*)(xr + 1024 + t * 4);
    float s = v0.x + v0.y + v0.z + v0.w + v1.x + v1.y + v1.z + v1.w;
    float q = v0.x*v0.x + v0.y*v0.y + v0.z*v0.z + v0.w*v0.w
            + v1.x*v1.x + v1.y*v1.y + v1.z*v1.z + v1.w*v1.w;
    #pragma unroll
    for (int o = 32; o; o >>= 1) { s += __shfl_xor(s, o); q += __shfl_xor(q, o); }
    __shared__ float ss[4], qq[4];
    if ((t & 63) == 0) { ss[t >> 6] = s; qq[t >> 6] = q; }
    __syncthreads();
    s = ss[0] + ss[1] + ss[2] + ss[3];
    q = qq[0] + qq[1] + qq[2] + qq[3];
    float mean = s * (1.f / DM);
    float var  = q * (1.f / DM) - mean * mean;
    float rstd = rsqrtf(var + EPS);
    u16* orow = xn + (size_t)row * DM;
    u16x4 o0 = { f2bf((v0.x-mean)*rstd), f2bf((v0.y-mean)*rstd),
                 f2bf((v0.z-mean)*rstd), f2bf((v0.w-mean)*rstd) };
    u16x4 o1 = { f2bf((v1.x-mean)*rstd), f2bf((v1.y-mean)*rstd),
                 f2bf((v1.z-mean)*rstd), f2bf((v1.w-mean)*rstd) };
    *(u16x4*)(orow + t * 4) = o0;
    *(u16x4*)(orow + 1024 + t * 4) = o1;
}

// ---------------------------------------------------------------------------
// 3) transpose + fp32->bf16: out[c][r] = in[r][c]  (per batch z)
__global__ __launch_bounds__(256) void transpose_cvt(const float* __restrict__ in,
                                                     u16* __restrict__ out,
                                                     int R, int C,
                                                     long inStride, long outStride) {
    in  += (size_t)blockIdx.z * inStride;
    out += (size_t)blockIdx.z * outStride;
    int r0 = blockIdx.y * 64, c0 = blockIdx.x * 64;
    __shared__ u16 tile[64][65];
    int t = threadIdx.x;
    #pragma unroll
    for (int it = 0; it < 4; ++it) {
        int idx = t + it * 256;          // 0..1023
        int rr = idx >> 4;
        int cc = (idx & 15) * 4;
        float4 v = *(const float4*)(in + (size_t)(r0 + rr) * C + c0 + cc);
        tile[rr][cc+0] = f2bf(v.x); tile[rr][cc+1] = f2bf(v.y);
        tile[rr][cc+2] = f2bf(v.z); tile[rr][cc+3] = f2bf(v.w);
    }
    __syncthreads();
    #pragma unroll
    for (int it = 0; it < 4; ++it) {
        int idx = t + it * 256;
        int oc  = idx >> 4;              // output row (= original col)
        int orr = (idx & 15) * 4;        // output col (= original row)
        u16x4 w = { tile[orr+0][oc], tile[orr+1][oc], tile[orr+2][oc], tile[orr+3][oc] };
        *(u16x4*)(out + (size_t)(c0 + oc) * R + r0 + orr) = w;
    }
}

// ---------------------------------------------------------------------------
// 4) QKV GEMM: Xn[2048][2048] (bf16) x Wt[6144][2048] (bf16, B^T) -> qkv bf16
//    epilogue: + bias, rotary (Q,K), store [which][h][s][128]
__global__ __launch_bounds__(256) void gemm_qkv(const u16* __restrict__ Xn,
                                                const u16* __restrict__ Wt,
                                                const float* __restrict__ bQ,
                                                const float* __restrict__ bK,
                                                const float* __restrict__ bV,
                                                const float2* __restrict__ rope,
                                                u16* __restrict__ qkv) {
    __shared__ u16 As[128 * 32], Bs[128 * 32];
    int m0 = blockIdx.x * 128;
    int nblk = blockIdx.y;                  // 0..47:  which = nblk>>4, h = nblk&15
    const u16* Bg = Wt + (size_t)nblk * 128 * 2048;
    int t = threadIdx.x, lane = t & 63, w = t >> 6;
    int wr = w >> 1, wc = w & 1;
    int cl = lane & 15, g = lane >> 4;
    f32x4 acc[4][4] = {};
    for (int k0 = 0; k0 < DM; k0 += 32) {
        #pragma unroll
        for (int j = 0; j < 2; ++j) {
            int idx = t + j * 256;
            int row = idx >> 2, slot = idx & 3;
            *(u16x8*)&As[row * 32 + slot * 8] =
                *(const u16x8*)(Xn + (size_t)(m0 + row) * DM + k0 + slot * 8);
            *(u16x8*)&Bs[row * 32 + slot * 8] =
                *(const u16x8*)(Bg + (size_t)row * DM + k0 + slot * 8);
        }
        __syncthreads();
        bf16x8 af[4], bfr[4];
        #pragma unroll
        for (int i = 0; i < 4; ++i)
            af[i] = as_bf(*(const u16x8*)&As[(wr*64 + i*16 + cl) * 32 + g * 8]);
        #pragma unroll
        for (int j = 0; j < 4; ++j)
            bfr[j] = as_bf(*(const u16x8*)&Bs[(wc*64 + j*16 + cl) * 32 + g * 8]);
        #pragma unroll
        for (int i = 0; i < 4; ++i)
            #pragma unroll
            for (int j = 0; j < 4; ++j)
                acc[i][j] = __builtin_amdgcn_mfma_f32_16x16x32_bf16(af[i], bfr[j], acc[i][j], 0, 0, 0);
        __syncthreads();
    }
    int which = nblk >> 4, h = nblk & 15;
    const float* bias = (which == 0) ? bQ : (which == 1) ? bK : bV;
    u16* outbase = qkv + (size_t)nblk * SEQ * DH;
    bool dorope = (which < 2);
    #pragma unroll
    for (int i = 0; i < 4; ++i)
        #pragma unroll
        for (int j = 0; j < 4; ++j) {
            int e = wc * 64 + j * 16 + cl;
            float bb = bias[h * DH + e];
            #pragma unroll
            for (int r = 0; r < 4; ++r) {
                int p = m0 + wr * 64 + i * 16 + g * 4 + r;
                float v = acc[i][j][r] + bb;
                if (dorope) {
                    float pv = __shfl_xor(v, 1);
                    float2 sc2 = rope[p * 64 + (e >> 1)];
                    v = (e & 1) ? (v * sc2.y + pv * sc2.x) : (v * sc2.y - pv * sc2.x);
                }
                outbase[(size_t)p * DH + e] = f2bf(v);
            }
        }
}

// ---------------------------------------------------------------------------
// 5) causal flash attention.  grid (SEQ/64, NH), 4 waves x 16 q-rows.
__global__ __launch_bounds__(256) void flash_kernel(const u16* __restrict__ Qg,
                                                    const u16* __restrict__ Kg,
                                                    const u16* __restrict__ Vg,
                                                    u16* __restrict__ Zg) {
    __shared__ u16 kt[64 * 128];       // K tile, rows kv (256B), slot-swizzled
    __shared__ u16 vt[128 * 64];       // V^T, rows e (128B), slot-swizzled
    __shared__ u16 pt[4][16 * 72];     // per-wave P, rows q-local (144B, padded)
    int h = blockIdx.y;
    int q0 = blockIdx.x * 64;
    int t = threadIdx.x, lane = t & 63, w = t >> 6;
    int cl = lane & 15, g = lane >> 4;
    int qw0 = q0 + w * 16;

    // Q fragments (rotary already applied)
    bf16x8 qf[4];
    #pragma unroll
    for (int st = 0; st < 4; ++st)
        qf[st] = as_bf(*(const u16x8*)(Qg + ((size_t)h * SEQ + qw0 + cl) * DH + st * 32 + g * 8));

    f32x4 acc[8] = {};
    float mrun[4] = { -3e38f, -3e38f, -3e38f, -3e38f };
    float lsum[4] = { 0.f, 0.f, 0.f, 0.f };

    for (int kv0 = 0; kv0 <= q0; kv0 += 64) {
        // stage K (swizzled row-major) and V^T (swizzled transpose)
        #pragma unroll
        for (int j = 0; j < 4; ++j) {
            int idx = t + j * 256;              // 0..1023
            int row = idx >> 4, slot = idx & 15;
            u16x8 kv8 = *(const u16x8*)(Kg + ((size_t)h * SEQ + kv0 + row) * DH + slot * 8);
            *(u16x8*)((char*)kt + row * 256 + ((slot ^ (row & 7)) * 16)) = kv8;
        }
        #pragma unroll
        for (int j = 0; j < 4; ++j) {
            int idx = t + j * 256;
            int kvr = idx >> 4, slotE = idx & 15;
            u16x8 v8 = *(const u16x8*)(Vg + ((size_t)h * SEQ + kv0 + kvr) * DH + slotE * 8);
            #pragma unroll
            for (int jj = 0; jj < 8; ++jj) {
                int e = slotE * 8 + jj;
                *(u16*)((char*)vt + e * 128 + (((kvr >> 3) ^ (e & 7)) * 16) + (kvr & 7) * 2) = v8[jj];
            }
        }
        __syncthreads();

        // S = Q K^T  (4 col-subtiles x 4 k-steps)
        f32x4 sc[4] = {};
        #pragma unroll
        for (int st = 0; st < 4; ++st)
            #pragma unroll
            for (int c = 0; c < 4; ++c) {
                int row = c * 16 + cl;
                bf16x8 kf = as_bf(*(const u16x8*)((char*)kt + row * 256 + (((st * 4 + g) ^ (row & 7)) * 16)));
                sc[c] = __builtin_amdgcn_mfma_f32_16x16x32_bf16(qf[st], kf, sc[c], 0, 0, 0);
            }

        // scale + causal mask + online softmax
        float pv[4][4], tm[4];
        #pragma unroll
        for (int r = 0; r < 4; ++r) tm[r] = -3e38f;
        #pragma unroll
        for (int c = 0; c < 4; ++c) {
            int col = kv0 + c * 16 + cl;
            #pragma unroll
            for (int r = 0; r < 4; ++r) {
                int qrow = qw0 + g * 4 + r;
                float sval = sc[c][r] * SCALE_INV;
                sval = (col <= qrow) ? sval : -3e38f;
                pv[c][r] = sval;
                tm[r] = fmaxf(tm[r], sval);
            }
        }
        #pragma unroll
        for (int m = 1; m <= 8; m <<= 1)
            #pragma unroll
            for (int r = 0; r < 4; ++r) tm[r] = fmaxf(tm[r], __shfl_xor(tm[r], m));
        float alpha[4], rs[4];
        #pragma unroll
        for (int r = 0; r < 4; ++r) {
            float mn = fmaxf(mrun[r], tm[r]);
            alpha[r] = __expf(mrun[r] - mn);
            mrun[r] = mn;
            rs[r] = 0.f;
        }
        #pragma unroll
        for (int c = 0; c < 4; ++c)
            #pragma unroll
            for (int r = 0; r < 4; ++r) {
                float p = __expf(pv[c][r] - mrun[r]);
                pv[c][r] = p;
                rs[r] += p;
            }
        #pragma unroll
        for (int m = 1; m <= 8; m <<= 1)
            #pragma unroll
            for (int r = 0; r < 4; ++r) rs[r] += __shfl_xor(rs[r], m);
        #pragma unroll
        for (int r = 0; r < 4; ++r) lsum[r] = lsum[r] * alpha[r] + rs[r];
        #pragma unroll
        for (int n = 0; n < 8; ++n)
            #pragma unroll
            for (int r = 0; r < 4; ++r) acc[n][r] *= alpha[r];

        // write P (bf16) to per-wave LDS, transposed-readable
        #pragma unroll
        for (int c = 0; c < 4; ++c)
            #pragma unroll
            for (int r = 0; r < 4; ++r)
                pt[w][(g * 4 + r) * 72 + c * 16 + cl] = f2bf(pv[c][r]);

        // PV
        bf16x8 pa[2];
        #pragma unroll
        for (int st = 0; st < 2; ++st)
            pa[st] = as_bf(*(const u16x8*)((char*)&pt[w][0] + cl * 144 + g * 16 + st * 64));
        #pragma unroll
        for (int n = 0; n < 8; ++n)
            #pragma unroll
            for (int st = 0; st < 2; ++st) {
                int e = n * 16 + cl;
                bf16x8 vf = as_bf(*(const u16x8*)((char*)vt + e * 128 + (((g + st * 4) ^ (e & 7)) * 16)));
                acc[n] = __builtin_amdgcn_mfma_f32_16x16x32_bf16(pa[st], vf, acc[n], 0, 0, 0);
            }
        __syncthreads();
    }

    float inv[4];
    #pragma unroll
    for (int r = 0; r < 4; ++r) inv[r] = 1.0f / lsum[r];
    #pragma unroll
    for (int n = 0; n < 8; ++n)
        #pragma unroll
        for (int r = 0; r < 4; ++r) {
            int q = qw0 + g * 4 + r;
            Zg[((size_t)h * SEQ + q) * DH + n * 16 + cl] = f2bf(acc[n][r] * inv[r]);
        }
}

// ---------------------------------------------------------------------------
// 6) output GEMM: z[16][2048][128] x Wot[2048][2048] (B^T: rows d, cols k) + bO
__global__ __launch_bounds__(256) void gemm_out(const u16* __restrict__ Z,
                                                const u16* __restrict__ Wot,
                                                const float* __restrict__ bO,
                                                float* __restrict__ out) {
    __shared__ u16 As[128 * 32], Bs[128 * 32];
    int m0 = blockIdx.x * 128, n0 = blockIdx.y * 128;
    int t = threadIdx.x, lane = t & 63, w = t >> 6;
    int wr = w >> 1, wc = w & 1;
    int cl = lane & 15, g = lane >> 4;
    f32x4 acc[4][4] = {};
    for (int k0 = 0; k0 < DM; k0 += 32) {
        int hh = k0 >> 7, e0 = k0 & 127;
        #pragma unroll
        for (int j = 0; j < 2; ++j) {
            int idx = t + j * 256;
            int row = idx >> 2, slot = idx & 3;
            *(u16x8*)&As[row * 32 + slot * 8] =
                *(const u16x8*)(Z + ((size_t)hh * SEQ + m0 + row) * DH + e0 + slot * 8);
            *(u16x8*)&Bs[row * 32 + slot * 8] =
                *(const u16x8*)(Wot + (size_t)(n0 + row) * DM + k0 + slot * 8);
        }
        __syncthreads();
        bf16x8 af[4], bfr[4];
        #pragma unroll
        for (int i = 0; i < 4; ++i)
            af[i] = as_bf(*(const u16x8*)&As[(wr*64 + i*16 + cl) * 32 + g * 8]);
        #pragma unroll
        for (int j = 0; j < 4; ++j)
            bfr[j] = as_bf(*(const u16x8*)&Bs[(wc*64 + j*16 + cl) * 32 + g * 8]);
        #pragma unroll
        for (int i = 0; i < 4; ++i)
            #pragma unroll
            for (int j = 0; j < 4; ++j)
                acc[i][j] = __builtin_amdgcn_mfma_f32_16x16x32_bf16(af[i], bfr[j], acc[i][j], 0, 0, 0);
        __syncthreads();
    }
    #pragma unroll
    for (int i = 0; i < 4; ++i)
        #pragma unroll
        for (int j = 0; j < 4; ++j) {
            int col = n0 + wc * 64 + j * 16 + cl;
            float bb = bO[col];
            #pragma unroll
            for (int r = 0; r < 4; ++r) {
                int p = m0 + wr * 64 + i * 16 + g * 4 + r;
                out[(size_t)p * DM + col] = acc[i][j][r] + bb;
            }
        }
}

// ---------------------------------------------------------------------------
extern "C" void kernel_launch(void* const* d_in, const int* in_sizes, int n_in,
                              void* d_out, int out_size, void* d_ws, size_t ws_size,
                              hipStream_t stream) {
    const float* resid = (const float*)d_in[0];
    const float* WQ = (const float*)d_in[1];
    const float* WK = (const float*)d_in[2];
    const float* WV = (const float*)d_in[3];
    const float* WO = (const float*)d_in[4];
    const float* bQ = (const float*)d_in[5];
    const float* bK = (const float*)d_in[6];
    const float* bV = (const float*)d_in[7];
    const float* bO = (const float*)d_in[8];
    float* out = (float*)d_out;
    char* ws = (char*)d_ws;

    float2* rope = (float2*)(ws);                        // 1 MB
    u16* xn   = (u16*)(ws + (1ll  << 20));               // 8 MB
    u16* Wt   = (u16*)(ws + (9ll  << 20));               // 24 MB  [3][16][128][2048]
    u16* Wot  = (u16*)(ws + (33ll << 20));               // 8 MB   [2048][2048]
    u16* qkv  = (u16*)(ws + (41ll << 20));               // 24 MB  [3][16][2048][128]
    u16* z    = (u16*)(ws + (65ll << 20));               // 8 MB   [16][2048][128]

    rope_kernel<<<SEQ, 64, 0, stream>>>(rope);
    ln_kernel<<<SEQ, 256, 0, stream>>>(resid, xn);

    long wstride = (long)DM * DH;                         // 262144
    transpose_cvt<<<dim3(2, 32, 16), 256, 0, stream>>>(WQ, Wt + 0ll * NH * wstride, DM, DH, wstride, wstride);
    transpose_cvt<<<dim3(2, 32, 16), 256, 0, stream>>>(WK, Wt + 1ll * NH * wstride, DM, DH, wstride, wstride);
    transpose_cvt<<<dim3(2, 32, 16), 256, 0, stream>>>(WV, Wt + 2ll * NH * wstride, DM, DH, wstride, wstride);
    transpose_cvt<<<dim3(32, 32, 1), 256, 0, stream>>>(WO, Wot, DM, DM, 0, 0);

    gemm_qkv<<<dim3(16, 48), 256, 0, stream>>>(xn, Wt, bQ, bK, bV, rope, qkv);

    const u16* Qg = qkv;
    const u16* Kg = qkv + 1ll * NH * SEQ * DH;
    const u16* Vg = qkv + 2ll * NH * SEQ * DH;
    flash_kernel<<<dim3(SEQ / 64, NH), 256, 0, stream>>>(Qg, Kg, Vg, z);

    gemm_out<<<dim3(16, 16), 256, 0, stream>>>(z, Wot, bO, out);
}

// Round 2
// 250.208 us; speedup vs baseline: 1.3919x; 1.3919x over previous
//
#include <hip/hip_runtime.h>
#include <hip/hip_bf16.h>

// ---------------------------------------------------------------------------
// Problem constants (BATCH=1)
#define SEQ    2048
#define DM     2048
#define NH     16
#define DH     128
#define EPS    1e-5f
#define SCALE_INV 0.08838834764831845f   // 1/sqrt(128)

typedef unsigned short u16;
typedef u16  u16x4  __attribute__((ext_vector_type(4)));
typedef u16  u16x8  __attribute__((ext_vector_type(8)));
typedef __bf16 bf16x8 __attribute__((ext_vector_type(8)));
typedef float f32x4 __attribute__((ext_vector_type(4)));

__device__ __forceinline__ u16 f2bf(float f) {
    unsigned int u = __builtin_bit_cast(unsigned int, f);
    u += 0x7fffu + ((u >> 16) & 1u);      // RNE
    return (u16)(u >> 16);
}
__device__ __forceinline__ bf16x8 as_bf(u16x8 v) { return __builtin_bit_cast(bf16x8, v); }

// ---------------------------------------------------------------------------
// 1) rotary table: tab[pos][i] = {sin(pos/10000^(i/64)), cos(...)}, i=0..63
__global__ void rope_kernel(float2* __restrict__ tab) {
    int i = threadIdx.x;                 // 0..63
    int pos = blockIdx.x;                // 0..2047
    float freq = powf(10000.f, (float)i * (1.f / 64.f));
    float ang = (float)pos / freq;
    tab[pos * 64 + i] = make_float2(sinf(ang), cosf(ang));
}

// ---------------------------------------------------------------------------
// 2) LayerNorm (center + rms of centered) fp32 -> bf16
__global__ __launch_bounds__(256) void ln_kernel(const float* __restrict__ x,
                                                 u16* __restrict__ xn) {
    int row = blockIdx.x, t = threadIdx.x;
    const float* xr = x + (size_t)row * DM;
    float4 v0 = *(const float4*)(xr + t * 4);
    float4 v1 = *(const float4*)(xr + 1024 + t * 4);
    float s = v0.x + v0.y + v0.z + v0.w + v1.x + v1.y + v1.z + v1.w;
    float q = v0.x*v0.x + v0.y*v0.y + v0.z*v0.z + v0.w*v0.w
            + v1.x*v1.x + v1.y*v1.y + v1.z*v1.z + v1.w*v1.w;
    #pragma unroll
    for (int o = 32; o; o >>= 1) { s += __shfl_xor(s, o); q += __shfl_xor(q, o); }
    __shared__ float ss[4], qq[4];
    if ((t & 63) == 0) { ss[t >> 6] = s; qq[t >> 6] = q; }
    __syncthreads();
    s = ss[0] + ss[1] + ss[2] + ss[3];
    q = qq[0] + qq[1] + qq[2] + qq[3];
    float mean = s * (1.f / DM);
    float var  = q * (1.f / DM) - mean * mean;
    float rstd = rsqrtf(var + EPS);
    u16* orow = xn + (size_t)row * DM;
    u16x4 o0 = { f2bf((v0.x-mean)*rstd), f2bf((v0.y-mean)*rstd),
                 f2bf((v0.z-mean)*rstd), f2bf((v0.w-mean)*rstd) };
    u16x4 o1 = { f2bf((v1.x-mean)*rstd), f2bf((v1.y-mean)*rstd),
                 f2bf((v1.z-mean)*rstd), f2bf((v1.w-mean)*rstd) };
    *(u16x4*)(orow + t * 4) = o0;
    *(u16x4*)(orow + 1024 + t * 4) = o1;
}

// ---------------------------------------------------------------------------
// 3) transpose + fp32->bf16: out[c][r] = in[r][c]  (per batch z)
__global__ __launch_bounds__(256) void transpose_cvt(const float* __restrict__ in,
                                                     u16* __restrict__ out,
                                                     int R, int C,
                                                     long inStride, long outStride) {
    in  += (size_t)blockIdx.z * inStride;
    out += (size_t)blockIdx.z * outStride;
    int r0 = blockIdx.y * 64, c0 = blockIdx.x * 64;
    __shared__ u16 tile[64][65];
    int t = threadIdx.x;
    #pragma unroll
    for (int it = 0; it < 4; ++it) {
        int idx = t + it * 256;          // 0..1023
        int rr = idx >> 4;
        int cc = (idx & 15) * 4;
        float4 v = *(const float4*)(in + (size_t)(r0 + rr) * C + c0 + cc);
        tile[rr][cc+0] = f2bf(v.x); tile[rr][cc+1] = f2bf(v.y);
        tile[rr][cc+2] = f2bf(v.z); tile[rr][cc+3] = f2bf(v.w);
    }
    __syncthreads();
    #pragma unroll
    for (int it = 0; it < 4; ++it) {
        int idx = t + it * 256;
        int oc  = idx >> 4;              // output row (= original col)
        int orr = (idx & 15) * 4;        // output col (= original row)
        u16x4 w = { tile[orr+0][oc], tile[orr+1][oc], tile[orr+2][oc], tile[orr+3][oc] };
        *(u16x4*)(out + (size_t)(c0 + oc) * R + r0 + orr) = w;
    }
}

// ---------------------------------------------------------------------------
// 4) QKV GEMM: Xn[2048][2048] (bf16) x Wt[6144][2048] (bf16, B^T) -> qkv bf16
//    epilogue: + bias, rotary (Q,K): store [which][h][s][128]
//              V: store TRANSPOSED Vt[h][e][s]
__global__ __launch_bounds__(256) void gemm_qkv(const u16* __restrict__ Xn,
                                                const u16* __restrict__ Wt,
                                                const float* __restrict__ bQ,
                                                const float* __restrict__ bK,
                                                const float* __restrict__ bV,
                                                const float2* __restrict__ rope,
                                                u16* __restrict__ qkv) {
    __shared__ u16 As[128 * 32], Bs[128 * 32];
    int m0 = blockIdx.x * 128;
    int nblk = blockIdx.y;                  // 0..47:  which = nblk>>4, h = nblk&15
    const u16* Bg = Wt + (size_t)nblk * 128 * 2048;
    int t = threadIdx.x, lane = t & 63, w = t >> 6;
    int wr = w >> 1, wc = w & 1;
    int cl = lane & 15, g = lane >> 4;
    f32x4 acc[4][4] = {};
    for (int k0 = 0; k0 < DM; k0 += 32) {
        #pragma unroll
        for (int j = 0; j < 2; ++j) {
            int idx = t + j * 256;
            int row = idx >> 2, slot = idx & 3;
            *(u16x8*)&As[row * 32 + slot * 8] =
                *(const u16x8*)(Xn + (size_t)(m0 + row) * DM + k0 + slot * 8);
            *(u16x8*)&Bs[row * 32 + slot * 8] =
                *(const u16x8*)(Bg + (size_t)row * DM + k0 + slot * 8);
        }
        __syncthreads();
        bf16x8 af[4], bfr[4];
        #pragma unroll
        for (int i = 0; i < 4; ++i)
            af[i] = as_bf(*(const u16x8*)&As[(wr*64 + i*16 + cl) * 32 + g * 8]);
        #pragma unroll
        for (int j = 0; j < 4; ++j)
            bfr[j] = as_bf(*(const u16x8*)&Bs[(wc*64 + j*16 + cl) * 32 + g * 8]);
        #pragma unroll
        for (int i = 0; i < 4; ++i)
            #pragma unroll
            for (int j = 0; j < 4; ++j)
                acc[i][j] = __builtin_amdgcn_mfma_f32_16x16x32_bf16(af[i], bfr[j], acc[i][j], 0, 0, 0);
        __syncthreads();
    }
    int which = nblk >> 4, h = nblk & 15;
    const float* bias = (which == 0) ? bQ : (which == 1) ? bK : bV;
    if (which == 2) {
        // V: store transposed Vt[h][e][s], vectorized along s (4 consecutive rows)
        u16* vbase = qkv + 2ll * NH * SEQ * DH + (size_t)h * DH * SEQ;
        #pragma unroll
        for (int i = 0; i < 4; ++i)
            #pragma unroll
            for (int j = 0; j < 4; ++j) {
                int e = wc * 64 + j * 16 + cl;
                float bb = bias[h * DH + e];
                int p0 = m0 + wr * 64 + i * 16 + g * 4;
                u16x4 o = { f2bf(acc[i][j][0] + bb), f2bf(acc[i][j][1] + bb),
                            f2bf(acc[i][j][2] + bb), f2bf(acc[i][j][3] + bb) };
                *(u16x4*)(vbase + (size_t)e * SEQ + p0) = o;
            }
    } else {
        u16* outbase = qkv + (size_t)nblk * SEQ * DH;
        #pragma unroll
        for (int i = 0; i < 4; ++i)
            #pragma unroll
            for (int j = 0; j < 4; ++j) {
                int e = wc * 64 + j * 16 + cl;
                float bb = bias[h * DH + e];
                #pragma unroll
                for (int r = 0; r < 4; ++r) {
                    int p = m0 + wr * 64 + i * 16 + g * 4 + r;
                    float v = acc[i][j][r] + bb;
                    float pv = __shfl_xor(v, 1);
                    float2 sc2 = rope[p * 64 + (e >> 1)];
                    v = (e & 1) ? (v * sc2.y + pv * sc2.x) : (v * sc2.y - pv * sc2.x);
                    outbase[(size_t)p * DH + e] = f2bf(v);
                }
            }
    }
}

// ---------------------------------------------------------------------------
// 5) causal flash attention.  grid (NH, SEQ/64), biggest q-tiles first.
//    4 waves x 16 q-rows; single-buffered LDS with async reg-staged prefetch.
__global__ __launch_bounds__(256) void flash_kernel(const u16* __restrict__ Qg,
                                                    const u16* __restrict__ Kg,
                                                    const u16* __restrict__ Vt,
                                                    u16* __restrict__ Zg) {
    __shared__ u16 kt[64 * 128];       // K tile, rows kv (256B), slot-swizzled
    __shared__ u16 vt[128 * 64];       // V^T tile, rows e (128B), slot-swizzled
    __shared__ u16 pt[4][16 * 72];     // per-wave P, rows q-local (144B, padded)
    int h = blockIdx.x;
    int nQ = gridDim.y;
    int q0 = (nQ - 1 - blockIdx.y) * 64;     // biggest first
    int t = threadIdx.x, lane = t & 63, w = t >> 6;
    int cl = lane & 15, g = lane >> 4;
    int qw0 = q0 + w * 16;
    const size_t hs = (size_t)h * SEQ;

    // Q fragments (rotary already applied)
    bf16x8 qf[4];
    #pragma unroll
    for (int st = 0; st < 4; ++st)
        qf[st] = as_bf(*(const u16x8*)(Qg + (hs + qw0 + cl) * DH + st * 32 + g * 8));

    f32x4 acc[8] = {};
    float mrun[4] = { -3e38f, -3e38f, -3e38f, -3e38f };
    float lsum[4] = { 0.f, 0.f, 0.f, 0.f };

    u16x8 kreg[4], vreg[4];
    auto load_tile = [&](int kv0) {
        #pragma unroll
        for (int j = 0; j < 4; ++j) {
            int idx = t + j * 256;
            kreg[j] = *(const u16x8*)(Kg + (hs + kv0 + (idx >> 4)) * DH + (idx & 15) * 8);
            vreg[j] = *(const u16x8*)(Vt + ((size_t)h * DH + (idx >> 3)) * SEQ + kv0 + (idx & 7) * 8);
        }
    };
    auto store_tile = [&]() {
        #pragma unroll
        for (int j = 0; j < 4; ++j) {
            int idx = t + j * 256;
            int row = idx >> 4, slot = idx & 15;
            *(u16x8*)((char*)kt + row * 256 + ((slot ^ (row & 7)) * 16)) = kreg[j];
            int e = idx >> 3, ch = idx & 7;
            *(u16x8*)((char*)vt + e * 128 + ((ch ^ (e & 7)) * 16)) = vreg[j];
        }
    };

    load_tile(0);
    store_tile();

    for (int kv0 = 0; kv0 <= q0; kv0 += 64) {
        __syncthreads();                    // LDS tile ready
        bool more = (kv0 + 64 <= q0);
        if (more) load_tile(kv0 + 64);      // async prefetch into regs

        // S = Q K^T  (4 col-subtiles x 4 k-steps)
        f32x4 sc[4] = {};
        #pragma unroll
        for (int st = 0; st < 4; ++st)
            #pragma unroll
            for (int c = 0; c < 4; ++c) {
                int row = c * 16 + cl;
                bf16x8 kf = as_bf(*(const u16x8*)((char*)kt + row * 256 + (((st * 4 + g) ^ (row & 7)) * 16)));
                sc[c] = __builtin_amdgcn_mfma_f32_16x16x32_bf16(qf[st], kf, sc[c], 0, 0, 0);
            }

        // scale + causal mask (diagonal tile only) + online softmax
        bool needmask = (kv0 + 63 > qw0);
        float pvv[4][4], tm[4];
        #pragma unroll
        for (int r = 0; r < 4; ++r) tm[r] = -3e38f;
        #pragma unroll
        for (int c = 0; c < 4; ++c) {
            int col = kv0 + c * 16 + cl;
            #pragma unroll
            for (int r = 0; r < 4; ++r) {
                int qrow = qw0 + g * 4 + r;
                float sval = sc[c][r] * SCALE_INV;
                if (needmask) sval = (col <= qrow) ? sval : -3e38f;
                pvv[c][r] = sval;
                tm[r] = fmaxf(tm[r], sval);
            }
        }
        #pragma unroll
        for (int m = 1; m <= 8; m <<= 1)
            #pragma unroll
            for (int r = 0; r < 4; ++r) tm[r] = fmaxf(tm[r], __shfl_xor(tm[r], m));
        float alpha[4], rs[4];
        #pragma unroll
        for (int r = 0; r < 4; ++r) {
            float mn = fmaxf(mrun[r], tm[r]);
            alpha[r] = __expf(mrun[r] - mn);
            mrun[r] = mn;
            rs[r] = 0.f;
        }
        #pragma unroll
        for (int c = 0; c < 4; ++c)
            #pragma unroll
            for (int r = 0; r < 4; ++r) {
                float p = __expf(pvv[c][r] - mrun[r]);
                pvv[c][r] = p;
                rs[r] += p;
            }
        #pragma unroll
        for (int m = 1; m <= 8; m <<= 1)
            #pragma unroll
            for (int r = 0; r < 4; ++r) rs[r] += __shfl_xor(rs[r], m);
        #pragma unroll
        for (int r = 0; r < 4; ++r) lsum[r] = lsum[r] * alpha[r] + rs[r];
        #pragma unroll
        for (int n = 0; n < 8; ++n)
            #pragma unroll
            for (int r = 0; r < 4; ++r) acc[n][r] *= alpha[r];

        // write P (bf16) to per-wave LDS, transposed-readable
        #pragma unroll
        for (int c = 0; c < 4; ++c)
            #pragma unroll
            for (int r = 0; r < 4; ++r)
                pt[w][(g * 4 + r) * 72 + c * 16 + cl] = f2bf(pvv[c][r]);

        // PV
        bf16x8 pa[2];
        #pragma unroll
        for (int ks = 0; ks < 2; ++ks)
            pa[ks] = as_bf(*(const u16x8*)((char*)&pt[w][0] + cl * 144 + ks * 64 + g * 16));
        #pragma unroll
        for (int n = 0; n < 8; ++n)
            #pragma unroll
            for (int ks = 0; ks < 2; ++ks) {
                int e = n * 16 + cl;
                bf16x8 vf = as_bf(*(const u16x8*)((char*)vt + e * 128 + (((ks * 4 + g) ^ (cl & 7)) * 16)));
                acc[n] = __builtin_amdgcn_mfma_f32_16x16x32_bf16(pa[ks], vf, acc[n], 0, 0, 0);
            }

        if (!more) break;
        __syncthreads();                    // all reads of LDS done
        store_tile();                       // write prefetched tile
    }

    float inv[4];
    #pragma unroll
    for (int r = 0; r < 4; ++r) inv[r] = 1.0f / lsum[r];
    #pragma unroll
    for (int n = 0; n < 8; ++n)
        #pragma unroll
        for (int r = 0; r < 4; ++r) {
            int q = qw0 + g * 4 + r;
            Zg[(hs + q) * DH + n * 16 + cl] = f2bf(acc[n][r] * inv[r]);
        }
}

// ---------------------------------------------------------------------------
// 6) output GEMM: z[16][2048][128] x Wot[2048][2048] (B^T: rows d, cols k) + bO
__global__ __launch_bounds__(256) void gemm_out(const u16* __restrict__ Z,
                                                const u16* __restrict__ Wot,
                                                const float* __restrict__ bO,
                                                float* __restrict__ out) {
    __shared__ u16 As[128 * 32], Bs[128 * 32];
    int m0 = blockIdx.x * 128, n0 = blockIdx.y * 128;
    int t = threadIdx.x, lane = t & 63, w = t >> 6;
    int wr = w >> 1, wc = w & 1;
    int cl = lane & 15, g = lane >> 4;
    f32x4 acc[4][4] = {};
    for (int k0 = 0; k0 < DM; k0 += 32) {
        int hh = k0 >> 7, e0 = k0 & 127;
        #pragma unroll
        for (int j = 0; j < 2; ++j) {
            int idx = t + j * 256;
            int row = idx >> 2, slot = idx & 3;
            *(u16x8*)&As[row * 32 + slot * 8] =
                *(const u16x8*)(Z + ((size_t)hh * SEQ + m0 + row) * DH + e0 + slot * 8);
            *(u16x8*)&Bs[row * 32 + slot * 8] =
                *(const u16x8*)(Wot + (size_t)(n0 + row) * DM + k0 + slot * 8);
        }
        __syncthreads();
        bf16x8 af[4], bfr[4];
        #pragma unroll
        for (int i = 0; i < 4; ++i)
            af[i] = as_bf(*(const u16x8*)&As[(wr*64 + i*16 + cl) * 32 + g * 8]);
        #pragma unroll
        for (int j = 0; j < 4; ++j)
            bfr[j] = as_bf(*(const u16x8*)&Bs[(wc*64 + j*16 + cl) * 32 + g * 8]);
        #pragma unroll
        for (int i = 0; i < 4; ++i)
            #pragma unroll
            for (int j = 0; j < 4; ++j)
                acc[i][j] = __builtin_amdgcn_mfma_f32_16x16x32_bf16(af[i], bfr[j], acc[i][j], 0, 0, 0);
        __syncthreads();
    }
    #pragma unroll
    for (int i = 0; i < 4; ++i)
        #pragma unroll
        for (int j = 0; j < 4; ++j) {
            int col = n0 + wc * 64 + j * 16 + cl;
            float bb = bO[col];
            #pragma unroll
            for (int r = 0; r < 4; ++r) {
                int p = m0 + wr * 64 + i * 16 + g * 4 + r;
                out[(size_t)p * DM + col] = acc[i][j][r] + bb;
            }
        }
}

// ---------------------------------------------------------------------------
extern "C" void kernel_launch(void* const* d_in, const int* in_sizes, int n_in,
                              void* d_out, int out_size, void* d_ws, size_t ws_size,
                              hipStream_t stream) {
    const float* resid = (const float*)d_in[0];
    const float* WQ = (const float*)d_in[1];
    const float* WK = (const float*)d_in[2];
    const float* WV = (const float*)d_in[3];
    const float* WO = (const float*)d_in[4];
    const float* bQ = (const float*)d_in[5];
    const float* bK = (const float*)d_in[6];
    const float* bV = (const float*)d_in[7];
    const float* bO = (const float*)d_in[8];
    float* out = (float*)d_out;
    char* ws = (char*)d_ws;

    float2* rope = (float2*)(ws);                        // 1 MB
    u16* xn   = (u16*)(ws + (1ll  << 20));               // 8 MB
    u16* Wt   = (u16*)(ws + (9ll  << 20));               // 24 MB  [3][16][128][2048]
    u16* Wot  = (u16*)(ws + (33ll << 20));               // 8 MB   [2048][2048]
    u16* qkv  = (u16*)(ws + (41ll << 20));               // 24 MB  [q][k][vT]
    u16* z    = (u16*)(ws + (65ll << 20));               // 8 MB   [16][2048][128]

    rope_kernel<<<SEQ, 64, 0, stream>>>(rope);
    ln_kernel<<<SEQ, 256, 0, stream>>>(resid, xn);

    long wstride = (long)DM * DH;                         // 262144
    transpose_cvt<<<dim3(2, 32, 16), 256, 0, stream>>>(WQ, Wt + 0ll * NH * wstride, DM, DH, wstride, wstride);
    transpose_cvt<<<dim3(2, 32, 16), 256, 0, stream>>>(WK, Wt + 1ll * NH * wstride, DM, DH, wstride, wstride);
    transpose_cvt<<<dim3(2, 32, 16), 256, 0, stream>>>(WV, Wt + 2ll * NH * wstride, DM, DH, wstride, wstride);
    transpose_cvt<<<dim3(32, 32, 1), 256, 0, stream>>>(WO, Wot, DM, DM, 0, 0);

    gemm_qkv<<<dim3(16, 48), 256, 0, stream>>>(xn, Wt, bQ, bK, bV, rope, qkv);

    const u16* Qg = qkv;
    const u16* Kg = qkv + 1ll * NH * SEQ * DH;
    const u16* Vt = qkv + 2ll * NH * SEQ * DH;
    flash_kernel<<<dim3(NH, SEQ / 64), 256, 0, stream>>>(Qg, Kg, Vt, z);

    gemm_out<<<dim3(16, 16), 256, 0, stream>>>(z, Wot, bO, out);
}

// Round 3
// 238.772 us; speedup vs baseline: 1.4585x; 1.0479x over previous
//
#include <hip/hip_runtime.h>
#include <hip/hip_bf16.h>

// ---------------------------------------------------------------------------
// Problem constants (BATCH=1)
#define SEQ    2048
#define DM     2048
#define NH     16
#define DH     128
#define EPS    1e-5f
#define SCALE_INV 0.08838834764831845f   // 1/sqrt(128)

typedef unsigned short u16;
typedef u16  u16x4  __attribute__((ext_vector_type(4)));
typedef u16  u16x8  __attribute__((ext_vector_type(8)));
typedef __bf16 bf16x8 __attribute__((ext_vector_type(8)));
typedef float f32x4 __attribute__((ext_vector_type(4)));

__device__ __forceinline__ u16 f2bf(float f) {
    unsigned int u = __builtin_bit_cast(unsigned int, f);
    u += 0x7fffu + ((u >> 16) & 1u);      // RNE
    return (u16)(u >> 16);
}
__device__ __forceinline__ bf16x8 as_bf(u16x8 v) { return __builtin_bit_cast(bf16x8, v); }

// async global->LDS, 16B per lane.  LDS dest must be wave-uniform base + lane*16.
__device__ __forceinline__ void gload16(const u16* g, u16* l) {
    __builtin_amdgcn_global_load_lds(
        (const __attribute__((address_space(1))) unsigned int*)g,
        (__attribute__((address_space(3))) unsigned int*)l, 16, 0, 0);
}

// ---------------------------------------------------------------------------
// 1) rotary table: tab[pos][i] = {sin(pos/10000^(i/64)), cos(...)}, i=0..63
__global__ void rope_kernel(float2* __restrict__ tab) {
    int i = threadIdx.x;                 // 0..63
    int pos = blockIdx.x;                // 0..2047
    float freq = powf(10000.f, (float)i * (1.f / 64.f));
    float ang = (float)pos / freq;
    tab[pos * 64 + i] = make_float2(sinf(ang), cosf(ang));
}

// ---------------------------------------------------------------------------
// 2) LayerNorm (center + rms of centered) fp32 -> bf16
__global__ __launch_bounds__(256) void ln_kernel(const float* __restrict__ x,
                                                 u16* __restrict__ xn) {
    int row = blockIdx.x, t = threadIdx.x;
    const float* xr = x + (size_t)row * DM;
    float4 v0 = *(const float4*)(xr + t * 4);
    float4 v1 = *(const float4*)(xr + 1024 + t * 4);
    float s = v0.x + v0.y + v0.z + v0.w + v1.x + v1.y + v1.z + v1.w;
    float q = v0.x*v0.x + v0.y*v0.y + v0.z*v0.z + v0.w*v0.w
            + v1.x*v1.x + v1.y*v1.y + v1.z*v1.z + v1.w*v1.w;
    #pragma unroll
    for (int o = 32; o; o >>= 1) { s += __shfl_xor(s, o); q += __shfl_xor(q, o); }
    __shared__ float ss[4], qq[4];
    if ((t & 63) == 0) { ss[t >> 6] = s; qq[t >> 6] = q; }
    __syncthreads();
    s = ss[0] + ss[1] + ss[2] + ss[3];
    q = qq[0] + qq[1] + qq[2] + qq[3];
    float mean = s * (1.f / DM);
    float var  = q * (1.f / DM) - mean * mean;
    float rstd = rsqrtf(var + EPS);
    u16* orow = xn + (size_t)row * DM;
    u16x4 o0 = { f2bf((v0.x-mean)*rstd), f2bf((v0.y-mean)*rstd),
                 f2bf((v0.z-mean)*rstd), f2bf((v0.w-mean)*rstd) };
    u16x4 o1 = { f2bf((v1.x-mean)*rstd), f2bf((v1.y-mean)*rstd),
                 f2bf((v1.z-mean)*rstd), f2bf((v1.w-mean)*rstd) };
    *(u16x4*)(orow + t * 4) = o0;
    *(u16x4*)(orow + 1024 + t * 4) = o1;
}

// ---------------------------------------------------------------------------
// 3) transpose + fp32->bf16: out[c][r] = in[r][c]  (per batch z)
__global__ __launch_bounds__(256) void transpose_cvt(const float* __restrict__ in,
                                                     u16* __restrict__ out,
                                                     int R, int C,
                                                     long inStride, long outStride) {
    in  += (size_t)blockIdx.z * inStride;
    out += (size_t)blockIdx.z * outStride;
    int r0 = blockIdx.y * 64, c0 = blockIdx.x * 64;
    __shared__ u16 tile[64][65];
    int t = threadIdx.x;
    #pragma unroll
    for (int it = 0; it < 4; ++it) {
        int idx = t + it * 256;          // 0..1023
        int rr = idx >> 4;
        int cc = (idx & 15) * 4;
        float4 v = *(const float4*)(in + (size_t)(r0 + rr) * C + c0 + cc);
        tile[rr][cc+0] = f2bf(v.x); tile[rr][cc+1] = f2bf(v.y);
        tile[rr][cc+2] = f2bf(v.z); tile[rr][cc+3] = f2bf(v.w);
    }
    __syncthreads();
    #pragma unroll
    for (int it = 0; it < 4; ++it) {
        int idx = t + it * 256;
        int oc  = idx >> 4;              // output row (= original col)
        int orr = (idx & 15) * 4;        // output col (= original row)
        u16x4 w = { tile[orr+0][oc], tile[orr+1][oc], tile[orr+2][oc], tile[orr+3][oc] };
        *(u16x4*)(out + (size_t)(c0 + oc) * R + r0 + orr) = w;
    }
}

// ---------------------------------------------------------------------------
// 4) QKV GEMM: Xn[2048][2048] (bf16) x Wt[6144][2048] (bf16, B^T) -> qkv bf16
//    global_load_lds staging (linear LDS dest, XOR-preswizzled global source).
//    epilogue: + bias, rotary (Q,K): store [which][h][s][128]
//              V: store TRANSPOSED Vt[h][e][s]
__global__ __launch_bounds__(256) void gemm_qkv(const u16* __restrict__ Xn,
                                                const u16* __restrict__ Wt,
                                                const float* __restrict__ bQ,
                                                const float* __restrict__ bK,
                                                const float* __restrict__ bV,
                                                const float2* __restrict__ rope,
                                                u16* __restrict__ qkv) {
    __shared__ u16 As[128 * 32], Bs[128 * 32];
    int m0 = blockIdx.x * 128;
    int nblk = blockIdx.y;                  // 0..47:  which = nblk>>4, h = nblk&15
    const u16* Bg = Wt + (size_t)nblk * 128 * 2048;
    int t = threadIdx.x, lane = t & 63, w = t >> 6;
    int wr = w >> 1, wc = w & 1;
    int cl = lane & 15, g = lane >> 4;
    int swz = cl & 3;                       // read-side slot XOR (row&3 == cl&3)
    f32x4 acc[4][4] = {};
    for (int k0 = 0; k0 < DM; k0 += 32) {
        #pragma unroll
        for (int j = 0; j < 2; ++j) {
            int idx = t + j * 256;
            int row = idx >> 2, slot = idx & 3;
            int slotS = slot ^ (row & 3);   // inverse swizzle on SOURCE (rule #21)
            gload16(Xn + (size_t)(m0 + row) * DM + k0 + slotS * 8, &As[idx * 8]);
            gload16(Bg + (size_t)row * DM + k0 + slotS * 8, &Bs[idx * 8]);
        }
        __syncthreads();
        bf16x8 af[4], bfr[4];
        #pragma unroll
        for (int i = 0; i < 4; ++i)
            af[i] = as_bf(*(const u16x8*)&As[(wr*64 + i*16 + cl) * 32 + (g ^ swz) * 8]);
        #pragma unroll
        for (int j = 0; j < 4; ++j)
            bfr[j] = as_bf(*(const u16x8*)&Bs[(wc*64 + j*16 + cl) * 32 + (g ^ swz) * 8]);
        #pragma unroll
        for (int i = 0; i < 4; ++i)
            #pragma unroll
            for (int j = 0; j < 4; ++j)
                acc[i][j] = __builtin_amdgcn_mfma_f32_16x16x32_bf16(af[i], bfr[j], acc[i][j], 0, 0, 0);
        __syncthreads();
    }
    int which = nblk >> 4, h = nblk & 15;
    const float* bias = (which == 0) ? bQ : (which == 1) ? bK : bV;
    if (which == 2) {
        // V: store transposed Vt[h][e][s], vectorized along s (4 consecutive rows)
        u16* vbase = qkv + 2ll * NH * SEQ * DH + (size_t)h * DH * SEQ;
        #pragma unroll
        for (int i = 0; i < 4; ++i)
            #pragma unroll
            for (int j = 0; j < 4; ++j) {
                int e = wc * 64 + j * 16 + cl;
                float bb = bias[h * DH + e];
                int p0 = m0 + wr * 64 + i * 16 + g * 4;
                u16x4 o = { f2bf(acc[i][j][0] + bb), f2bf(acc[i][j][1] + bb),
                            f2bf(acc[i][j][2] + bb), f2bf(acc[i][j][3] + bb) };
                *(u16x4*)(vbase + (size_t)e * SEQ + p0) = o;
            }
    } else {
        u16* outbase = qkv + (size_t)nblk * SEQ * DH;
        #pragma unroll
        for (int i = 0; i < 4; ++i)
            #pragma unroll
            for (int j = 0; j < 4; ++j) {
                int e = wc * 64 + j * 16 + cl;
                float bb = bias[h * DH + e];
                #pragma unroll
                for (int r = 0; r < 4; ++r) {
                    int p = m0 + wr * 64 + i * 16 + g * 4 + r;
                    float v = acc[i][j][r] + bb;
                    float pv = __shfl_xor(v, 1);
                    float2 sc2 = rope[p * 64 + (e >> 1)];
                    v = (e & 1) ? (v * sc2.y + pv * sc2.x) : (v * sc2.y - pv * sc2.x);
                    outbase[(size_t)p * DH + e] = f2bf(v);
                }
            }
    }
}

// ---------------------------------------------------------------------------
// 5) causal flash attention.  grid (NH, SEQ/64), biggest q-tiles first.
//    4 waves x 16 q-rows; single-buffered LDS with async reg-staged prefetch.
__global__ __launch_bounds__(256) void flash_kernel(const u16* __restrict__ Qg,
                                                    const u16* __restrict__ Kg,
                                                    const u16* __restrict__ Vt,
                                                    u16* __restrict__ Zg) {
    __shared__ u16 kt[64 * 128];       // K tile, rows kv (256B), slot-swizzled
    __shared__ u16 vt[128 * 64];       // V^T tile, rows e (128B), slot-swizzled
    __shared__ u16 pt[4][16 * 72];     // per-wave P, rows q-local (144B, padded)
    int h = blockIdx.x;
    int nQ = gridDim.y;
    int q0 = (nQ - 1 - blockIdx.y) * 64;     // biggest first
    int t = threadIdx.x, lane = t & 63, w = t >> 6;
    int cl = lane & 15, g = lane >> 4;
    int qw0 = q0 + w * 16;
    const size_t hs = (size_t)h * SEQ;

    // Q fragments (rotary already applied)
    bf16x8 qf[4];
    #pragma unroll
    for (int st = 0; st < 4; ++st)
        qf[st] = as_bf(*(const u16x8*)(Qg + (hs + qw0 + cl) * DH + st * 32 + g * 8));

    f32x4 acc[8] = {};
    float mrun[4] = { -3e38f, -3e38f, -3e38f, -3e38f };
    float lsum[4] = { 0.f, 0.f, 0.f, 0.f };

    u16x8 kreg[4], vreg[4];
    auto load_tile = [&](int kv0) {
        #pragma unroll
        for (int j = 0; j < 4; ++j) {
            int idx = t + j * 256;
            kreg[j] = *(const u16x8*)(Kg + (hs + kv0 + (idx >> 4)) * DH + (idx & 15) * 8);
            vreg[j] = *(const u16x8*)(Vt + ((size_t)h * DH + (idx >> 3)) * SEQ + kv0 + (idx & 7) * 8);
        }
    };
    auto store_tile = [&]() {
        #pragma unroll
        for (int j = 0; j < 4; ++j) {
            int idx = t + j * 256;
            int row = idx >> 4, slot = idx & 15;
            *(u16x8*)((char*)kt + row * 256 + ((slot ^ (row & 7)) * 16)) = kreg[j];
            int e = idx >> 3, ch = idx & 7;
            *(u16x8*)((char*)vt + e * 128 + ((ch ^ (e & 7)) * 16)) = vreg[j];
        }
    };

    load_tile(0);
    store_tile();

    for (int kv0 = 0; kv0 <= q0; kv0 += 64) {
        __syncthreads();                    // LDS tile ready
        bool more = (kv0 + 64 <= q0);
        if (more) load_tile(kv0 + 64);      // async prefetch into regs

        // S = Q K^T  (4 col-subtiles x 4 k-steps)
        f32x4 sc[4] = {};
        #pragma unroll
        for (int st = 0; st < 4; ++st)
            #pragma unroll
            for (int c = 0; c < 4; ++c) {
                int row = c * 16 + cl;
                bf16x8 kf = as_bf(*(const u16x8*)((char*)kt + row * 256 + (((st * 4 + g) ^ (row & 7)) * 16)));
                sc[c] = __builtin_amdgcn_mfma_f32_16x16x32_bf16(qf[st], kf, sc[c], 0, 0, 0);
            }

        // scale + causal mask (diagonal tile only) + online softmax
        bool needmask = (kv0 + 63 > qw0);
        float pvv[4][4], tm[4];
        #pragma unroll
        for (int r = 0; r < 4; ++r) tm[r] = -3e38f;
        #pragma unroll
        for (int c = 0; c < 4; ++c) {
            int col = kv0 + c * 16 + cl;
            #pragma unroll
            for (int r = 0; r < 4; ++r) {
                int qrow = qw0 + g * 4 + r;
                float sval = sc[c][r] * SCALE_INV;
                if (needmask) sval = (col <= qrow) ? sval : -3e38f;
                pvv[c][r] = sval;
                tm[r] = fmaxf(tm[r], sval);
            }
        }
        #pragma unroll
        for (int m = 1; m <= 8; m <<= 1)
            #pragma unroll
            for (int r = 0; r < 4; ++r) tm[r] = fmaxf(tm[r], __shfl_xor(tm[r], m));
        float alpha[4], rs[4];
        #pragma unroll
        for (int r = 0; r < 4; ++r) {
            float mn = fmaxf(mrun[r], tm[r]);
            alpha[r] = __expf(mrun[r] - mn);
            mrun[r] = mn;
            rs[r] = 0.f;
        }
        #pragma unroll
        for (int c = 0; c < 4; ++c)
            #pragma unroll
            for (int r = 0; r < 4; ++r) {
                float p = __expf(pvv[c][r] - mrun[r]);
                pvv[c][r] = p;
                rs[r] += p;
            }
        #pragma unroll
        for (int m = 1; m <= 8; m <<= 1)
            #pragma unroll
            for (int r = 0; r < 4; ++r) rs[r] += __shfl_xor(rs[r], m);
        #pragma unroll
        for (int r = 0; r < 4; ++r) lsum[r] = lsum[r] * alpha[r] + rs[r];
        #pragma unroll
        for (int n = 0; n < 8; ++n)
            #pragma unroll
            for (int r = 0; r < 4; ++r) acc[n][r] *= alpha[r];

        // write P (bf16) to per-wave LDS, transposed-readable
        #pragma unroll
        for (int c = 0; c < 4; ++c)
            #pragma unroll
            for (int r = 0; r < 4; ++r)
                pt[w][(g * 4 + r) * 72 + c * 16 + cl] = f2bf(pvv[c][r]);

        // PV
        bf16x8 pa[2];
        #pragma unroll
        for (int ks = 0; ks < 2; ++ks)
            pa[ks] = as_bf(*(const u16x8*)((char*)&pt[w][0] + cl * 144 + ks * 64 + g * 16));
        #pragma unroll
        for (int n = 0; n < 8; ++n)
            #pragma unroll
            for (int ks = 0; ks < 2; ++ks) {
                int e = n * 16 + cl;
                bf16x8 vf = as_bf(*(const u16x8*)((char*)vt + e * 128 + (((ks * 4 + g) ^ (e & 7)) * 16)));
                acc[n] = __builtin_amdgcn_mfma_f32_16x16x32_bf16(pa[ks], vf, acc[n], 0, 0, 0);
            }

        if (!more) break;
        __syncthreads();                    // all reads of LDS done
        store_tile();                       // write prefetched tile
    }

    float inv[4];
    #pragma unroll
    for (int r = 0; r < 4; ++r) inv[r] = 1.0f / lsum[r];
    #pragma unroll
    for (int n = 0; n < 8; ++n)
        #pragma unroll
        for (int r = 0; r < 4; ++r) {
            int q = qw0 + g * 4 + r;
            Zg[(hs + q) * DH + n * 16 + cl] = f2bf(acc[n][r] * inv[r]);
        }
}

// ---------------------------------------------------------------------------
// 6) output GEMM: z[16][2048][128] x Wot[2048][2048] (B^T: rows d, cols k) + bO
__global__ __launch_bounds__(256) void gemm_out(const u16* __restrict__ Z,
                                                const u16* __restrict__ Wot,
                                                const float* __restrict__ bO,
                                                float* __restrict__ out) {
    __shared__ u16 As[128 * 32], Bs[128 * 32];
    int m0 = blockIdx.x * 128, n0 = blockIdx.y * 128;
    int t = threadIdx.x, lane = t & 63, w = t >> 6;
    int wr = w >> 1, wc = w & 1;
    int cl = lane & 15, g = lane >> 4;
    int swz = cl & 3;
    f32x4 acc[4][4] = {};
    for (int k0 = 0; k0 < DM; k0 += 32) {
        int hh = k0 >> 7, e0 = k0 & 127;
        #pragma unroll
        for (int j = 0; j < 2; ++j) {
            int idx = t + j * 256;
            int row = idx >> 2, slot = idx & 3;
            int slotS = slot ^ (row & 3);
            gload16(Z + ((size_t)hh * SEQ + m0 + row) * DH + e0 + slotS * 8, &As[idx * 8]);
            gload16(Wot + (size_t)(n0 + row) * DM + k0 + slotS * 8, &Bs[idx * 8]);
        }
        __syncthreads();
        bf16x8 af[4], bfr[4];
        #pragma unroll
        for (int i = 0; i < 4; ++i)
            af[i] = as_bf(*(const u16x8*)&As[(wr*64 + i*16 + cl) * 32 + (g ^ swz) * 8]);
        #pragma unroll
        for (int j = 0; j < 4; ++j)
            bfr[j] = as_bf(*(const u16x8*)&Bs[(wc*64 + j*16 + cl) * 32 + (g ^ swz) * 8]);
        #pragma unroll
        for (int i = 0; i < 4; ++i)
            #pragma unroll
            for (int j = 0; j < 4; ++j)
                acc[i][j] = __builtin_amdgcn_mfma_f32_16x16x32_bf16(af[i], bfr[j], acc[i][j], 0, 0, 0);
        __syncthreads();
    }
    #pragma unroll
    for (int i = 0; i < 4; ++i)
        #pragma unroll
        for (int j = 0; j < 4; ++j) {
            int col = n0 + wc * 64 + j * 16 + cl;
            float bb = bO[col];
            #pragma unroll
            for (int r = 0; r < 4; ++r) {
                int p = m0 + wr * 64 + i * 16 + g * 4 + r;
                out[(size_t)p * DM + col] = acc[i][j][r] + bb;
            }
        }
}

// ---------------------------------------------------------------------------
extern "C" void kernel_launch(void* const* d_in, const int* in_sizes, int n_in,
                              void* d_out, int out_size, void* d_ws, size_t ws_size,
                              hipStream_t stream) {
    const float* resid = (const float*)d_in[0];
    const float* WQ = (const float*)d_in[1];
    const float* WK = (const float*)d_in[2];
    const float* WV = (const float*)d_in[3];
    const float* WO = (const float*)d_in[4];
    const float* bQ = (const float*)d_in[5];
    const float* bK = (const float*)d_in[6];
    const float* bV = (const float*)d_in[7];
    const float* bO = (const float*)d_in[8];
    float* out = (float*)d_out;
    char* ws = (char*)d_ws;

    float2* rope = (float2*)(ws);                        // 1 MB
    u16* xn   = (u16*)(ws + (1ll  << 20));               // 8 MB
    u16* Wt   = (u16*)(ws + (9ll  << 20));               // 24 MB  [3][16][128][2048]
    u16* Wot  = (u16*)(ws + (33ll << 20));               // 8 MB   [2048][2048]
    u16* qkv  = (u16*)(ws + (41ll << 20));               // 24 MB  [q][k][vT]
    u16* z    = (u16*)(ws + (65ll << 20));               // 8 MB   [16][2048][128]

    rope_kernel<<<SEQ, 64, 0, stream>>>(rope);
    ln_kernel<<<SEQ, 256, 0, stream>>>(resid, xn);

    long wstride = (long)DM * DH;                         // 262144
    transpose_cvt<<<dim3(2, 32, 16), 256, 0, stream>>>(WQ, Wt + 0ll * NH * wstride, DM, DH, wstride, wstride);
    transpose_cvt<<<dim3(2, 32, 16), 256, 0, stream>>>(WK, Wt + 1ll * NH * wstride, DM, DH, wstride, wstride);
    transpose_cvt<<<dim3(2, 32, 16), 256, 0, stream>>>(WV, Wt + 2ll * NH * wstride, DM, DH, wstride, wstride);
    transpose_cvt<<<dim3(32, 32, 1), 256, 0, stream>>>(WO, Wot, DM, DM, 0, 0);

    gemm_qkv<<<dim3(16, 48), 256, 0, stream>>>(xn, Wt, bQ, bK, bV, rope, qkv);

    const u16* Qg = qkv;
    const u16* Kg = qkv + 1ll * NH * SEQ * DH;
    const u16* Vt = qkv + 2ll * NH * SEQ * DH;
    flash_kernel<<<dim3(NH, SEQ / 64), 256, 0, stream>>>(Qg, Kg, Vt, z);

    gemm_out<<<dim3(16, 16), 256, 0, stream>>>(z, Wot, bO, out);
}

// Round 4
// 232.385 us; speedup vs baseline: 1.4986x; 1.0275x over previous
//
#include <hip/hip_runtime.h>
#include <hip/hip_bf16.h>

// ---------------------------------------------------------------------------
// Problem constants (BATCH=1)
#define SEQ    2048
#define DM     2048
#define NH     16
#define DH     128
#define EPS    1e-5f
#define SCALE_INV 0.08838834764831845f   // 1/sqrt(128)

typedef unsigned short u16;
typedef u16  u16x4  __attribute__((ext_vector_type(4)));
typedef u16  u16x8  __attribute__((ext_vector_type(8)));
typedef __bf16 bf16x8 __attribute__((ext_vector_type(8)));
typedef float f32x4 __attribute__((ext_vector_type(4)));

__device__ __forceinline__ u16 f2bf(float f) {
    unsigned int u = __builtin_bit_cast(unsigned int, f);
    u += 0x7fffu + ((u >> 16) & 1u);      // RNE
    return (u16)(u >> 16);
}
__device__ __forceinline__ bf16x8 as_bf(u16x8 v) { return __builtin_bit_cast(bf16x8, v); }

// async global->LDS, 16B per lane.  LDS dest must be wave-uniform base + lane*16.
__device__ __forceinline__ void gload16(const u16* g, u16* l) {
    __builtin_amdgcn_global_load_lds(
        (const __attribute__((address_space(1))) unsigned int*)g,
        (__attribute__((address_space(3))) unsigned int*)l, 16, 0, 0);
}

#define VMCNT(N) asm volatile("s_waitcnt vmcnt(" #N ")" ::: "memory")
#define LGKMCNT0 asm volatile("s_waitcnt lgkmcnt(0)" ::: "memory")
#define SCHEDBAR __builtin_amdgcn_sched_barrier(0)
#define BARRIER  __builtin_amdgcn_s_barrier()

// ---------------------------------------------------------------------------
// 1) rotary table: tab[pos][i] = {sin(pos/10000^(i/64)), cos(...)}, i=0..63
__global__ void rope_kernel(float2* __restrict__ tab) {
    int i = threadIdx.x;                 // 0..63
    int pos = blockIdx.x;                // 0..2047
    float freq = powf(10000.f, (float)i * (1.f / 64.f));
    float ang = (float)pos / freq;
    tab[pos * 64 + i] = make_float2(sinf(ang), cosf(ang));
}

// ---------------------------------------------------------------------------
// 2) LayerNorm (center + rms of centered) fp32 -> bf16
__global__ __launch_bounds__(256) void ln_kernel(const float* __restrict__ x,
                                                 u16* __restrict__ xn) {
    int row = blockIdx.x, t = threadIdx.x;
    const float* xr = x + (size_t)row * DM;
    float4 v0 = *(const float4*)(xr + t * 4);
    float4 v1 = *(const float4*)(xr + 1024 + t * 4);
    float s = v0.x + v0.y + v0.z + v0.w + v1.x + v1.y + v1.z + v1.w;
    float q = v0.x*v0.x + v0.y*v0.y + v0.z*v0.z + v0.w*v0.w
            + v1.x*v1.x + v1.y*v1.y + v1.z*v1.z + v1.w*v1.w;
    #pragma unroll
    for (int o = 32; o; o >>= 1) { s += __shfl_xor(s, o); q += __shfl_xor(q, o); }
    __shared__ float ss[4], qq[4];
    if ((t & 63) == 0) { ss[t >> 6] = s; qq[t >> 6] = q; }
    __syncthreads();
    s = ss[0] + ss[1] + ss[2] + ss[3];
    q = qq[0] + qq[1] + qq[2] + qq[3];
    float mean = s * (1.f / DM);
    float var  = q * (1.f / DM) - mean * mean;
    float rstd = rsqrtf(var + EPS);
    u16* orow = xn + (size_t)row * DM;
    u16x4 o0 = { f2bf((v0.x-mean)*rstd), f2bf((v0.y-mean)*rstd),
                 f2bf((v0.z-mean)*rstd), f2bf((v0.w-mean)*rstd) };
    u16x4 o1 = { f2bf((v1.x-mean)*rstd), f2bf((v1.y-mean)*rstd),
                 f2bf((v1.z-mean)*rstd), f2bf((v1.w-mean)*rstd) };
    *(u16x4*)(orow + t * 4) = o0;
    *(u16x4*)(orow + 1024 + t * 4) = o1;
}

// ---------------------------------------------------------------------------
// 3a) combined QKV weight transpose + cvt: out[z][c][r] = W[z](r,c), z=which*16+h
__global__ __launch_bounds__(256) void transpose_qkv(const float* __restrict__ WQ,
                                                     const float* __restrict__ WK,
                                                     const float* __restrict__ WV,
                                                     u16* __restrict__ out) {
    int z = blockIdx.z, which = z >> 4, h = z & 15;
    const float* in = ((which == 0) ? WQ : (which == 1) ? WK : WV) + (size_t)h * DM * DH;
    u16* o = out + (size_t)z * DM * DH;
    int r0 = blockIdx.y * 64, c0 = blockIdx.x * 64;
    __shared__ u16 tile[64][65];
    int t = threadIdx.x;
    #pragma unroll
    for (int it = 0; it < 4; ++it) {
        int idx = t + it * 256;
        int rr = idx >> 4, cc = (idx & 15) * 4;
        float4 v = *(const float4*)(in + (size_t)(r0 + rr) * DH + c0 + cc);
        tile[rr][cc+0] = f2bf(v.x); tile[rr][cc+1] = f2bf(v.y);
        tile[rr][cc+2] = f2bf(v.z); tile[rr][cc+3] = f2bf(v.w);
    }
    __syncthreads();
    #pragma unroll
    for (int it = 0; it < 4; ++it) {
        int idx = t + it * 256;
        int oc = idx >> 4, orr = (idx & 15) * 4;
        u16x4 w = { tile[orr+0][oc], tile[orr+1][oc], tile[orr+2][oc], tile[orr+3][oc] };
        *(u16x4*)(o + (size_t)(c0 + oc) * DM + r0 + orr) = w;
    }
}

// 3b) WO transpose: out[c][r] = in[r][c], 2048x2048
__global__ __launch_bounds__(256) void transpose_wo(const float* __restrict__ in,
                                                    u16* __restrict__ out) {
    int r0 = blockIdx.y * 64, c0 = blockIdx.x * 64;
    __shared__ u16 tile[64][65];
    int t = threadIdx.x;
    #pragma unroll
    for (int it = 0; it < 4; ++it) {
        int idx = t + it * 256;
        int rr = idx >> 4, cc = (idx & 15) * 4;
        float4 v = *(const float4*)(in + (size_t)(r0 + rr) * DM + c0 + cc);
        tile[rr][cc+0] = f2bf(v.x); tile[rr][cc+1] = f2bf(v.y);
        tile[rr][cc+2] = f2bf(v.z); tile[rr][cc+3] = f2bf(v.w);
    }
    __syncthreads();
    #pragma unroll
    for (int it = 0; it < 4; ++it) {
        int idx = t + it * 256;
        int oc = idx >> 4, orr = (idx & 15) * 4;
        u16x4 w = { tile[orr+0][oc], tile[orr+1][oc], tile[orr+2][oc], tile[orr+3][oc] };
        *(u16x4*)(out + (size_t)(c0 + oc) * DM + r0 + orr) = w;
    }
}

// ---------------------------------------------------------------------------
// 4) QKV GEMM, 2-phase double-buffer with counted vmcnt (T3/T4 minimum).
//    Xn[2048][2048] x Wt[6144][2048] (B^T) -> q/k (rotary) / v (transposed)
__global__ __launch_bounds__(256) void gemm_qkv(const u16* __restrict__ Xn,
                                                const u16* __restrict__ Wt,
                                                const float* __restrict__ bQ,
                                                const float* __restrict__ bK,
                                                const float* __restrict__ bV,
                                                const float2* __restrict__ rope,
                                                u16* __restrict__ qkv) {
    __shared__ u16 As[2 * 128 * 32], Bs[2 * 128 * 32];
    int m0 = blockIdx.x * 128;
    int nblk = blockIdx.y;                  // 0..47:  which = nblk>>4, h = nblk&15
    const u16* Bg = Wt + (size_t)nblk * 128 * 2048;
    int t = threadIdx.x, lane = t & 63, w = t >> 6;
    int wr = w >> 1, wc = w & 1;
    int cl = lane & 15, g = lane >> 4;
    int swz = (cl >> 1) & 3;                // read-side slot XOR ((row>>1)&3, row=..+cl)

    auto stage = [&](int buf, int k0) {
        u16* Ab = As + buf * (128 * 32);
        u16* Bb = Bs + buf * (128 * 32);
        #pragma unroll
        for (int j = 0; j < 2; ++j) {
            int idx = t + j * 256;
            int row = idx >> 2, slot = idx & 3;
            int slotS = slot ^ ((row >> 1) & 3);   // inverse swizzle on SOURCE
            gload16(Xn + (size_t)(m0 + row) * DM + k0 + slotS * 8, Ab + idx * 8);
            gload16(Bg + (size_t)row * DM + k0 + slotS * 8, Bb + idx * 8);
        }
    };

    f32x4 acc[4][4] = {};
    stage(0, 0);
    int cur = 0;
    for (int k0 = 0; k0 < DM; k0 += 32) {
        bool more = (k0 + 32 < DM);
        if (more) {
            stage(cur ^ 1, k0 + 32);
            VMCNT(4);                       // current tile's 4 loads done; next 4 in flight
        } else {
            VMCNT(0);
        }
        SCHEDBAR;
        BARRIER;
        const u16* Ac = As + cur * (128 * 32);
        const u16* Bc = Bs + cur * (128 * 32);
        bf16x8 af[4], bfr[4];
        #pragma unroll
        for (int i = 0; i < 4; ++i)
            af[i] = as_bf(*(const u16x8*)&Ac[(wr*64 + i*16 + cl) * 32 + (g ^ swz) * 8]);
        #pragma unroll
        for (int j = 0; j < 4; ++j)
            bfr[j] = as_bf(*(const u16x8*)&Bc[(wc*64 + j*16 + cl) * 32 + (g ^ swz) * 8]);
        #pragma unroll
        for (int i = 0; i < 4; ++i)
            #pragma unroll
            for (int j = 0; j < 4; ++j)
                acc[i][j] = __builtin_amdgcn_mfma_f32_16x16x32_bf16(af[i], bfr[j], acc[i][j], 0, 0, 0);
        LGKMCNT0;                           // all ds_reads of this wave retired
        SCHEDBAR;
        BARRIER;                            // safe to overwrite buf[cur] next iter
        cur ^= 1;
    }

    int which = nblk >> 4, h = nblk & 15;
    const float* bias = (which == 0) ? bQ : (which == 1) ? bK : bV;
    if (which == 2) {
        // V: store transposed Vt[h][e][s], vectorized along s (4 consecutive rows)
        u16* vbase = qkv + 2ll * NH * SEQ * DH + (size_t)h * DH * SEQ;
        #pragma unroll
        for (int i = 0; i < 4; ++i)
            #pragma unroll
            for (int j = 0; j < 4; ++j) {
                int e = wc * 64 + j * 16 + cl;
                float bb = bias[h * DH + e];
                int p0 = m0 + wr * 64 + i * 16 + g * 4;
                u16x4 o = { f2bf(acc[i][j][0] + bb), f2bf(acc[i][j][1] + bb),
                            f2bf(acc[i][j][2] + bb), f2bf(acc[i][j][3] + bb) };
                *(u16x4*)(vbase + (size_t)e * SEQ + p0) = o;
            }
    } else {
        u16* outbase = qkv + (size_t)nblk * SEQ * DH;
        #pragma unroll
        for (int i = 0; i < 4; ++i)
            #pragma unroll
            for (int j = 0; j < 4; ++j) {
                int e = wc * 64 + j * 16 + cl;
                float bb = bias[h * DH + e];
                #pragma unroll
                for (int r = 0; r < 4; ++r) {
                    int p = m0 + wr * 64 + i * 16 + g * 4 + r;
                    float v = acc[i][j][r] + bb;
                    float pv = __shfl_xor(v, 1);
                    float2 sc2 = rope[p * 64 + (e >> 1)];
                    v = (e & 1) ? (v * sc2.y + pv * sc2.x) : (v * sc2.y - pv * sc2.x);
                    outbase[(size_t)p * DH + e] = f2bf(v);
                }
            }
    }
}

// ---------------------------------------------------------------------------
// 5) causal flash attention.  grid (NH, SEQ/64), biggest q-tiles first.
//    4 waves x 16 q-rows; single-buffered LDS with async reg-staged prefetch.
__global__ __launch_bounds__(256) void flash_kernel(const u16* __restrict__ Qg,
                                                    const u16* __restrict__ Kg,
                                                    const u16* __restrict__ Vt,
                                                    u16* __restrict__ Zg) {
    __shared__ u16 kt[64 * 128];       // K tile, rows kv (256B), slot-swizzled
    __shared__ u16 vt[128 * 64];       // V^T tile, rows e (128B), slot-swizzled
    __shared__ u16 pt[4][16 * 72];     // per-wave P, rows q-local (144B, padded)
    int h = blockIdx.x;
    int nQ = gridDim.y;
    int q0 = (nQ - 1 - blockIdx.y) * 64;     // biggest first
    int t = threadIdx.x, lane = t & 63, w = t >> 6;
    int cl = lane & 15, g = lane >> 4;
    int qw0 = q0 + w * 16;
    const size_t hs = (size_t)h * SEQ;

    // Q fragments (rotary already applied)
    bf16x8 qf[4];
    #pragma unroll
    for (int st = 0; st < 4; ++st)
        qf[st] = as_bf(*(const u16x8*)(Qg + (hs + qw0 + cl) * DH + st * 32 + g * 8));

    f32x4 acc[8] = {};
    float mrun[4] = { -3e38f, -3e38f, -3e38f, -3e38f };
    float lsum[4] = { 0.f, 0.f, 0.f, 0.f };

    u16x8 kreg[4], vreg[4];
    auto load_tile = [&](int kv0) {
        #pragma unroll
        for (int j = 0; j < 4; ++j) {
            int idx = t + j * 256;
            kreg[j] = *(const u16x8*)(Kg + (hs + kv0 + (idx >> 4)) * DH + (idx & 15) * 8);
            vreg[j] = *(const u16x8*)(Vt + ((size_t)h * DH + (idx >> 3)) * SEQ + kv0 + (idx & 7) * 8);
        }
    };
    auto store_tile = [&]() {
        #pragma unroll
        for (int j = 0; j < 4; ++j) {
            int idx = t + j * 256;
            int row = idx >> 4, slot = idx & 15;
            *(u16x8*)((char*)kt + row * 256 + ((slot ^ (row & 7)) * 16)) = kreg[j];
            int e = idx >> 3, ch = idx & 7;
            *(u16x8*)((char*)vt + e * 128 + ((ch ^ (e & 7)) * 16)) = vreg[j];
        }
    };

    load_tile(0);
    store_tile();

    for (int kv0 = 0; kv0 <= q0; kv0 += 64) {
        __syncthreads();                    // LDS tile ready
        bool more = (kv0 + 64 <= q0);
        if (more) load_tile(kv0 + 64);      // async prefetch into regs

        // S = Q K^T  (4 col-subtiles x 4 k-steps)
        f32x4 sc[4] = {};
        #pragma unroll
        for (int st = 0; st < 4; ++st)
            #pragma unroll
            for (int c = 0; c < 4; ++c) {
                int row = c * 16 + cl;
                bf16x8 kf = as_bf(*(const u16x8*)((char*)kt + row * 256 + (((st * 4 + g) ^ (row & 7)) * 16)));
                sc[c] = __builtin_amdgcn_mfma_f32_16x16x32_bf16(qf[st], kf, sc[c], 0, 0, 0);
            }

        // scale + causal mask (diagonal tile only) + online softmax
        bool needmask = (kv0 + 63 > qw0);
        float pvv[4][4], tm[4];
        #pragma unroll
        for (int r = 0; r < 4; ++r) tm[r] = -3e38f;
        #pragma unroll
        for (int c = 0; c < 4; ++c) {
            int col = kv0 + c * 16 + cl;
            #pragma unroll
            for (int r = 0; r < 4; ++r) {
                int qrow = qw0 + g * 4 + r;
                float sval = sc[c][r] * SCALE_INV;
                if (needmask) sval = (col <= qrow) ? sval : -3e38f;
                pvv[c][r] = sval;
                tm[r] = fmaxf(tm[r], sval);
            }
        }
        #pragma unroll
        for (int m = 1; m <= 8; m <<= 1)
            #pragma unroll
            for (int r = 0; r < 4; ++r) tm[r] = fmaxf(tm[r], __shfl_xor(tm[r], m));
        float alpha[4], rs[4];
        #pragma unroll
        for (int r = 0; r < 4; ++r) {
            float mn = fmaxf(mrun[r], tm[r]);
            alpha[r] = __expf(mrun[r] - mn);
            mrun[r] = mn;
            rs[r] = 0.f;
        }
        #pragma unroll
        for (int c = 0; c < 4; ++c)
            #pragma unroll
            for (int r = 0; r < 4; ++r) {
                float p = __expf(pvv[c][r] - mrun[r]);
                pvv[c][r] = p;
                rs[r] += p;
            }
        #pragma unroll
        for (int m = 1; m <= 8; m <<= 1)
            #pragma unroll
            for (int r = 0; r < 4; ++r) rs[r] += __shfl_xor(rs[r], m);
        #pragma unroll
        for (int r = 0; r < 4; ++r) lsum[r] = lsum[r] * alpha[r] + rs[r];
        #pragma unroll
        for (int n = 0; n < 8; ++n)
            #pragma unroll
            for (int r = 0; r < 4; ++r) acc[n][r] *= alpha[r];

        // write P (bf16) to per-wave LDS, transposed-readable
        #pragma unroll
        for (int c = 0; c < 4; ++c)
            #pragma unroll
            for (int r = 0; r < 4; ++r)
                pt[w][(g * 4 + r) * 72 + c * 16 + cl] = f2bf(pvv[c][r]);

        // PV
        bf16x8 pa[2];
        #pragma unroll
        for (int ks = 0; ks < 2; ++ks)
            pa[ks] = as_bf(*(const u16x8*)((char*)&pt[w][0] + cl * 144 + ks * 64 + g * 16));
        #pragma unroll
        for (int n = 0; n < 8; ++n)
            #pragma unroll
            for (int ks = 0; ks < 2; ++ks) {
                int e = n * 16 + cl;
                bf16x8 vf = as_bf(*(const u16x8*)((char*)vt + e * 128 + (((ks * 4 + g) ^ (e & 7)) * 16)));
                acc[n] = __builtin_amdgcn_mfma_f32_16x16x32_bf16(pa[ks], vf, acc[n], 0, 0, 0);
            }

        if (!more) break;
        __syncthreads();                    // all reads of LDS done
        store_tile();                       // write prefetched tile
    }

    float inv[4];
    #pragma unroll
    for (int r = 0; r < 4; ++r) inv[r] = 1.0f / lsum[r];
    #pragma unroll
    for (int n = 0; n < 8; ++n)
        #pragma unroll
        for (int r = 0; r < 4; ++r) {
            int q = qw0 + g * 4 + r;
            Zg[(hs + q) * DH + n * 16 + cl] = f2bf(acc[n][r] * inv[r]);
        }
}

// ---------------------------------------------------------------------------
// 6) output GEMM (2-phase dbuf): z[16][2048][128] x Wot[2048][2048] (B^T) + bO
__global__ __launch_bounds__(256) void gemm_out(const u16* __restrict__ Z,
                                                const u16* __restrict__ Wot,
                                                const float* __restrict__ bO,
                                                float* __restrict__ out) {
    __shared__ u16 As[2 * 128 * 32], Bs[2 * 128 * 32];
    int m0 = blockIdx.x * 128, n0 = blockIdx.y * 128;
    int t = threadIdx.x, lane = t & 63, w = t >> 6;
    int wr = w >> 1, wc = w & 1;
    int cl = lane & 15, g = lane >> 4;
    int swz = (cl >> 1) & 3;

    auto stage = [&](int buf, int k0) {
        u16* Ab = As + buf * (128 * 32);
        u16* Bb = Bs + buf * (128 * 32);
        int hh = k0 >> 7, e0 = k0 & 127;
        #pragma unroll
        for (int j = 0; j < 2; ++j) {
            int idx = t + j * 256;
            int row = idx >> 2, slot = idx & 3;
            int slotS = slot ^ ((row >> 1) & 3);
            gload16(Z + ((size_t)hh * SEQ + m0 + row) * DH + e0 + slotS * 8, Ab + idx * 8);
            gload16(Wot + (size_t)(n0 + row) * DM + k0 + slotS * 8, Bb + idx * 8);
        }
    };

    f32x4 acc[4][4] = {};
    stage(0, 0);
    int cur = 0;
    for (int k0 = 0; k0 < DM; k0 += 32) {
        bool more = (k0 + 32 < DM);
        if (more) {
            stage(cur ^ 1, k0 + 32);
            VMCNT(4);
        } else {
            VMCNT(0);
        }
        SCHEDBAR;
        BARRIER;
        const u16* Ac = As + cur * (128 * 32);
        const u16* Bc = Bs + cur * (128 * 32);
        bf16x8 af[4], bfr[4];
        #pragma unroll
        for (int i = 0; i < 4; ++i)
            af[i] = as_bf(*(const u16x8*)&Ac[(wr*64 + i*16 + cl) * 32 + (g ^ swz) * 8]);
        #pragma unroll
        for (int j = 0; j < 4; ++j)
            bfr[j] = as_bf(*(const u16x8*)&Bc[(wc*64 + j*16 + cl) * 32 + (g ^ swz) * 8]);
        #pragma unroll
        for (int i = 0; i < 4; ++i)
            #pragma unroll
            for (int j = 0; j < 4; ++j)
                acc[i][j] = __builtin_amdgcn_mfma_f32_16x16x32_bf16(af[i], bfr[j], acc[i][j], 0, 0, 0);
        LGKMCNT0;
        SCHEDBAR;
        BARRIER;
        cur ^= 1;
    }
    #pragma unroll
    for (int i = 0; i < 4; ++i)
        #pragma unroll
        for (int j = 0; j < 4; ++j) {
            int col = n0 + wc * 64 + j * 16 + cl;
            float bb = bO[col];
            #pragma unroll
            for (int r = 0; r < 4; ++r) {
                int p = m0 + wr * 64 + i * 16 + g * 4 + r;
                out[(size_t)p * DM + col] = acc[i][j][r] + bb;
            }
        }
}

// ---------------------------------------------------------------------------
extern "C" void kernel_launch(void* const* d_in, const int* in_sizes, int n_in,
                              void* d_out, int out_size, void* d_ws, size_t ws_size,
                              hipStream_t stream) {
    const float* resid = (const float*)d_in[0];
    const float* WQ = (const float*)d_in[1];
    const float* WK = (const float*)d_in[2];
    const float* WV = (const float*)d_in[3];
    const float* WO = (const float*)d_in[4];
    const float* bQ = (const float*)d_in[5];
    const float* bK = (const float*)d_in[6];
    const float* bV = (const float*)d_in[7];
    const float* bO = (const float*)d_in[8];
    float* out = (float*)d_out;
    char* ws = (char*)d_ws;

    float2* rope = (float2*)(ws);                        // 1 MB
    u16* xn   = (u16*)(ws + (1ll  << 20));               // 8 MB
    u16* Wt   = (u16*)(ws + (9ll  << 20));               // 24 MB  [3][16][128][2048]
    u16* Wot  = (u16*)(ws + (33ll << 20));               // 8 MB   [2048][2048]
    u16* qkv  = (u16*)(ws + (41ll << 20));               // 24 MB  [q][k][vT]
    u16* z    = (u16*)(ws + (65ll << 20));               // 8 MB   [16][2048][128]

    rope_kernel<<<SEQ, 64, 0, stream>>>(rope);
    ln_kernel<<<SEQ, 256, 0, stream>>>(resid, xn);

    transpose_qkv<<<dim3(2, 32, 48), 256, 0, stream>>>(WQ, WK, WV, Wt);
    transpose_wo<<<dim3(32, 32, 1), 256, 0, stream>>>(WO, Wot);

    gemm_qkv<<<dim3(16, 48), 256, 0, stream>>>(xn, Wt, bQ, bK, bV, rope, qkv);

    const u16* Qg = qkv;
    const u16* Kg = qkv + 1ll * NH * SEQ * DH;
    const u16* Vt = qkv + 2ll * NH * SEQ * DH;
    flash_kernel<<<dim3(NH, SEQ / 64), 256, 0, stream>>>(Qg, Kg, Vt, z);

    gemm_out<<<dim3(16, 16), 256, 0, stream>>>(z, Wot, bO, out);
}

// Round 5
// 210.319 us; speedup vs baseline: 1.6559x; 1.1049x over previous
//
#include <hip/hip_runtime.h>
#include <hip/hip_bf16.h>

// ---------------------------------------------------------------------------
// Problem constants (BATCH=1)
#define SEQ    2048
#define DM     2048
#define NH     16
#define DH     128
#define EPS    1e-5f
#define SCALE_INV 0.08838834764831845f   // 1/sqrt(128)

typedef unsigned short u16;
typedef u16  u16x4  __attribute__((ext_vector_type(4)));
typedef u16  u16x8  __attribute__((ext_vector_type(8)));
typedef __bf16 bf16x8 __attribute__((ext_vector_type(8)));
typedef float f32x4 __attribute__((ext_vector_type(4)));

__device__ __forceinline__ u16 f2bf(float f) {
    unsigned int u = __builtin_bit_cast(unsigned int, f);
    u += 0x7fffu + ((u >> 16) & 1u);      // RNE
    return (u16)(u >> 16);
}
__device__ __forceinline__ bf16x8 as_bf(u16x8 v) { return __builtin_bit_cast(bf16x8, v); }

// async global->LDS, 16B per lane.  LDS dest must be wave-uniform base + lane*16.
__device__ __forceinline__ void gload16(const u16* g, u16* l) {
    __builtin_amdgcn_global_load_lds(
        (const __attribute__((address_space(1))) unsigned int*)g,
        (__attribute__((address_space(3))) unsigned int*)l, 16, 0, 0);
}

#define VMCNT(N) asm volatile("s_waitcnt vmcnt(" #N ")" ::: "memory")
#define LGKMCNT0 asm volatile("s_waitcnt lgkmcnt(0)" ::: "memory")
#define SCHEDBAR __builtin_amdgcn_sched_barrier(0)
#define BARRIER  __builtin_amdgcn_s_barrier()

// ---------------------------------------------------------------------------
// 1) rotary table: tab[pos][i] = {sin(pos/10000^(i/64)), cos(...)}, i=0..63
__global__ void rope_kernel(float2* __restrict__ tab) {
    int i = threadIdx.x;                 // 0..63
    int pos = blockIdx.x;                // 0..2047
    float freq = powf(10000.f, (float)i * (1.f / 64.f));
    float ang = (float)pos / freq;
    tab[pos * 64 + i] = make_float2(sinf(ang), cosf(ang));
}

// ---------------------------------------------------------------------------
// 2) LayerNorm (center + rms of centered) fp32 -> bf16
__global__ __launch_bounds__(256) void ln_kernel(const float* __restrict__ x,
                                                 u16* __restrict__ xn) {
    int row = blockIdx.x, t = threadIdx.x;
    const float* xr = x + (size_t)row * DM;
    float4 v0 = *(const float4*)(xr + t * 4);
    float4 v1 = *(const float4*)(xr + 1024 + t * 4);
    float s = v0.x + v0.y + v0.z + v0.w + v1.x + v1.y + v1.z + v1.w;
    float q = v0.x*v0.x + v0.y*v0.y + v0.z*v0.z + v0.w*v0.w
            + v1.x*v1.x + v1.y*v1.y + v1.z*v1.z + v1.w*v1.w;
    #pragma unroll
    for (int o = 32; o; o >>= 1) { s += __shfl_xor(s, o); q += __shfl_xor(q, o); }
    __shared__ float ss[4], qq[4];
    if ((t & 63) == 0) { ss[t >> 6] = s; qq[t >> 6] = q; }
    __syncthreads();
    s = ss[0] + ss[1] + ss[2] + ss[3];
    q = qq[0] + qq[1] + qq[2] + qq[3];
    float mean = s * (1.f / DM);
    float var  = q * (1.f / DM) - mean * mean;
    float rstd = rsqrtf(var + EPS);
    u16* orow = xn + (size_t)row * DM;
    u16x4 o0 = { f2bf((v0.x-mean)*rstd), f2bf((v0.y-mean)*rstd),
                 f2bf((v0.z-mean)*rstd), f2bf((v0.w-mean)*rstd) };
    u16x4 o1 = { f2bf((v1.x-mean)*rstd), f2bf((v1.y-mean)*rstd),
                 f2bf((v1.z-mean)*rstd), f2bf((v1.w-mean)*rstd) };
    *(u16x4*)(orow + t * 4) = o0;
    *(u16x4*)(orow + 1024 + t * 4) = o1;
}

// ---------------------------------------------------------------------------
// 3a) combined QKV weight transpose + cvt: out[z][c][r] = W[z](r,c), z=which*16+h
__global__ __launch_bounds__(256) void transpose_qkv(const float* __restrict__ WQ,
                                                     const float* __restrict__ WK,
                                                     const float* __restrict__ WV,
                                                     u16* __restrict__ out) {
    int z = blockIdx.z, which = z >> 4, h = z & 15;
    const float* in = ((which == 0) ? WQ : (which == 1) ? WK : WV) + (size_t)h * DM * DH;
    u16* o = out + (size_t)z * DM * DH;
    int r0 = blockIdx.y * 64, c0 = blockIdx.x * 64;
    __shared__ u16 tile[64][65];
    int t = threadIdx.x;
    #pragma unroll
    for (int it = 0; it < 4; ++it) {
        int idx = t + it * 256;
        int rr = idx >> 4, cc = (idx & 15) * 4;
        float4 v = *(const float4*)(in + (size_t)(r0 + rr) * DH + c0 + cc);
        tile[rr][cc+0] = f2bf(v.x); tile[rr][cc+1] = f2bf(v.y);
        tile[rr][cc+2] = f2bf(v.z); tile[rr][cc+3] = f2bf(v.w);
    }
    __syncthreads();
    #pragma unroll
    for (int it = 0; it < 4; ++it) {
        int idx = t + it * 256;
        int oc = idx >> 4, orr = (idx & 15) * 4;
        u16x4 w = { tile[orr+0][oc], tile[orr+1][oc], tile[orr+2][oc], tile[orr+3][oc] };
        *(u16x4*)(o + (size_t)(c0 + oc) * DM + r0 + orr) = w;
    }
}

// 3b) WO transpose: out[c][r] = in[r][c], 2048x2048
__global__ __launch_bounds__(256) void transpose_wo(const float* __restrict__ in,
                                                    u16* __restrict__ out) {
    int r0 = blockIdx.y * 64, c0 = blockIdx.x * 64;
    __shared__ u16 tile[64][65];
    int t = threadIdx.x;
    #pragma unroll
    for (int it = 0; it < 4; ++it) {
        int idx = t + it * 256;
        int rr = idx >> 4, cc = (idx & 15) * 4;
        float4 v = *(const float4*)(in + (size_t)(r0 + rr) * DM + c0 + cc);
        tile[rr][cc+0] = f2bf(v.x); tile[rr][cc+1] = f2bf(v.y);
        tile[rr][cc+2] = f2bf(v.z); tile[rr][cc+3] = f2bf(v.w);
    }
    __syncthreads();
    #pragma unroll
    for (int it = 0; it < 4; ++it) {
        int idx = t + it * 256;
        int oc = idx >> 4, orr = (idx & 15) * 4;
        u16x4 w = { tile[orr+0][oc], tile[orr+1][oc], tile[orr+2][oc], tile[orr+3][oc] };
        *(u16x4*)(out + (size_t)(c0 + oc) * DM + r0 + orr) = w;
    }
}

// ---------------------------------------------------------------------------
// 4) QKV GEMM, 256x256 tile, BK=64, 8 waves (2x4), dbuf LDS + counted pipeline.
//    Xn[2048][2048] x Wt[6144][2048] (B^T rows = output cols) -> q/k/vT
__global__ __launch_bounds__(512, 2) void gemm_qkv(const u16* __restrict__ Xn,
                                                   const u16* __restrict__ Wt,
                                                   const float* __restrict__ bQ,
                                                   const float* __restrict__ bK,
                                                   const float* __restrict__ bV,
                                                   const float2* __restrict__ rope,
                                                   u16* __restrict__ qkv) {
    __shared__ u16 As[2][256 * 64], Bs[2][256 * 64];      // 128 KB total
    // T1: bijective XCD swizzle, 192 blocks / 8 XCDs = 24 per chunk
    int id = blockIdx.x;
    int swz = (id & 7) * 24 + (id >> 3);
    int bx = swz & 7, by = swz >> 3;                       // bx: M-tile, by: N-tile
    int m0 = bx * 256, n0 = by * 256;

    int t = threadIdx.x, lane = t & 63, wid = t >> 6;
    int wr = wid >> 2, wc = wid & 3;                       // 2 x 4 wave grid
    int cl = lane & 15, g = lane >> 4;

    auto stage = [&](int buf, int kt) {
        const u16* xa = Xn + (size_t)kt * 64;
        const u16* xb = Wt + (size_t)kt * 64;
        #pragma unroll
        for (int j = 0; j < 4; ++j) {
            int idx = t + j * 512;                 // 0..2047
            int row = idx >> 3;                    // 0..255
            int slotS = (idx & 7) ^ (row & 7);     // inverse swizzle on SOURCE
            gload16(xa + (size_t)(m0 + row) * DM + slotS * 8, &As[buf][idx * 8]);
            gload16(xb + (size_t)(n0 + row) * DM + slotS * 8, &Bs[buf][idx * 8]);
        }
    };

    f32x4 acc[8][4] = {};
    stage(0, 0);
    VMCNT(0);
    BARRIER;

    for (int kt = 0; kt < 32; ++kt) {
        int p = kt & 1;
        bool more = (kt + 1 < 32);
        bf16x8 bfr[4][2], af[4][2];
        // B frags: rows wc*64 + nj*16 + cl  (read once per tile)
        #pragma unroll
        for (int nj = 0; nj < 4; ++nj)
            #pragma unroll
            for (int kk = 0; kk < 2; ++kk) {
                int row = wc * 64 + nj * 16 + cl;
                int s = (kk * 4 + g) ^ (row & 7);
                bfr[nj][kk] = as_bf(*(const u16x8*)&Bs[p][row * 64 + s * 8]);
            }
        // A frags, m-half 0
        #pragma unroll
        for (int mi = 0; mi < 4; ++mi)
            #pragma unroll
            for (int kk = 0; kk < 2; ++kk) {
                int row = wr * 128 + mi * 16 + cl;
                int s = (kk * 4 + g) ^ (row & 7);
                af[mi][kk] = as_bf(*(const u16x8*)&As[p][row * 64 + s * 8]);
            }
        if (more) stage(p ^ 1, kt + 1);            // issue next tile early
        __builtin_amdgcn_s_setprio(1);
        #pragma unroll
        for (int mi = 0; mi < 4; ++mi)
            #pragma unroll
            for (int nj = 0; nj < 4; ++nj)
                #pragma unroll
                for (int kk = 0; kk < 2; ++kk)
                    acc[mi][nj] = __builtin_amdgcn_mfma_f32_16x16x32_bf16(af[mi][kk], bfr[nj][kk], acc[mi][nj], 0, 0, 0);
        __builtin_amdgcn_s_setprio(0);
        // A frags, m-half 1 (reuse registers)
        #pragma unroll
        for (int mi = 0; mi < 4; ++mi)
            #pragma unroll
            for (int kk = 0; kk < 2; ++kk) {
                int row = wr * 128 + 64 + mi * 16 + cl;
                int s = (kk * 4 + g) ^ (row & 7);
                af[mi][kk] = as_bf(*(const u16x8*)&As[p][row * 64 + s * 8]);
            }
        __builtin_amdgcn_s_setprio(1);
        #pragma unroll
        for (int mi = 0; mi < 4; ++mi)
            #pragma unroll
            for (int nj = 0; nj < 4; ++nj)
                #pragma unroll
                for (int kk = 0; kk < 2; ++kk)
                    acc[4 + mi][nj] = __builtin_amdgcn_mfma_f32_16x16x32_bf16(af[mi][kk], bfr[nj][kk], acc[4 + mi][nj], 0, 0, 0);
        __builtin_amdgcn_s_setprio(0);
        VMCNT(0);                                  // next tile's loads (aged) done
        SCHEDBAR;
        BARRIER;                                   // buf p free; buf p^1 ready
    }

    // epilogue: cols n0 + wc*64 + nj*16 + cl span 2 heads of one 'which'
    int which = n0 >> 11;
    const float* bias = (which == 0) ? bQ : (which == 1) ? bK : bV;
    #pragma unroll
    for (int i = 0; i < 8; ++i)
        #pragma unroll
        for (int nj = 0; nj < 4; ++nj) {
            int eg = n0 + wc * 64 + nj * 16 + cl;       // global col in [0,6144)
            int h = (eg >> 7) & 15;
            int e = eg & 127;
            float bb = bias[h * DH + e];
            int p0 = m0 + wr * 128 + i * 16 + g * 4;
            if (which == 2) {
                u16* vbase = qkv + 2ll * NH * SEQ * DH + (size_t)h * DH * SEQ;
                u16x4 o = { f2bf(acc[i][nj][0] + bb), f2bf(acc[i][nj][1] + bb),
                            f2bf(acc[i][nj][2] + bb), f2bf(acc[i][nj][3] + bb) };
                *(u16x4*)(vbase + (size_t)e * SEQ + p0) = o;
            } else {
                u16* outbase = qkv + ((size_t)which * 16 + h) * SEQ * DH;
                #pragma unroll
                for (int r = 0; r < 4; ++r) {
                    int pp = p0 + r;
                    float v = acc[i][nj][r] + bb;
                    float pv = __shfl_xor(v, 1);
                    float2 sc2 = rope[pp * 64 + (e >> 1)];
                    v = (e & 1) ? (v * sc2.y + pv * sc2.x) : (v * sc2.y - pv * sc2.x);
                    outbase[(size_t)pp * DH + e] = f2bf(v);
                }
            }
        }
}

// ---------------------------------------------------------------------------
// 5) causal flash attention.  grid (NH, SEQ/64), biggest q-tiles first.
//    4 waves x 16 q-rows; single-buffered LDS with async reg-staged prefetch.
__global__ __launch_bounds__(256) void flash_kernel(const u16* __restrict__ Qg,
                                                    const u16* __restrict__ Kg,
                                                    const u16* __restrict__ Vt,
                                                    u16* __restrict__ Zg) {
    __shared__ u16 kt[64 * 128];       // K tile, rows kv (256B), slot-swizzled
    __shared__ u16 vt[128 * 64];       // V^T tile, rows e (128B), slot-swizzled
    __shared__ u16 pt[4][16 * 72];     // per-wave P, rows q-local (144B, padded)
    int h = blockIdx.x;
    int nQ = gridDim.y;
    int q0 = (nQ - 1 - blockIdx.y) * 64;     // biggest first
    int t = threadIdx.x, lane = t & 63, w = t >> 6;
    int cl = lane & 15, g = lane >> 4;
    int qw0 = q0 + w * 16;
    const size_t hs = (size_t)h * SEQ;

    // Q fragments (rotary already applied)
    bf16x8 qf[4];
    #pragma unroll
    for (int st = 0; st < 4; ++st)
        qf[st] = as_bf(*(const u16x8*)(Qg + (hs + qw0 + cl) * DH + st * 32 + g * 8));

    f32x4 acc[8] = {};
    float mrun[4] = { -3e38f, -3e38f, -3e38f, -3e38f };
    float lsum[4] = { 0.f, 0.f, 0.f, 0.f };

    u16x8 kreg[4], vreg[4];
    auto load_tile = [&](int kv0) {
        #pragma unroll
        for (int j = 0; j < 4; ++j) {
            int idx = t + j * 256;
            kreg[j] = *(const u16x8*)(Kg + (hs + kv0 + (idx >> 4)) * DH + (idx & 15) * 8);
            vreg[j] = *(const u16x8*)(Vt + ((size_t)h * DH + (idx >> 3)) * SEQ + kv0 + (idx & 7) * 8);
        }
    };
    auto store_tile = [&]() {
        #pragma unroll
        for (int j = 0; j < 4; ++j) {
            int idx = t + j * 256;
            int row = idx >> 4, slot = idx & 15;
            *(u16x8*)((char*)kt + row * 256 + ((slot ^ (row & 7)) * 16)) = kreg[j];
            int e = idx >> 3, ch = idx & 7;
            *(u16x8*)((char*)vt + e * 128 + ((ch ^ (e & 7)) * 16)) = vreg[j];
        }
    };

    load_tile(0);
    store_tile();

    for (int kv0 = 0; kv0 <= q0; kv0 += 64) {
        __syncthreads();                    // LDS tile ready
        bool more = (kv0 + 64 <= q0);
        if (more) load_tile(kv0 + 64);      // async prefetch into regs

        // S = Q K^T  (4 col-subtiles x 4 k-steps)
        f32x4 sc[4] = {};
        #pragma unroll
        for (int st = 0; st < 4; ++st)
            #pragma unroll
            for (int c = 0; c < 4; ++c) {
                int row = c * 16 + cl;
                bf16x8 kf = as_bf(*(const u16x8*)((char*)kt + row * 256 + (((st * 4 + g) ^ (row & 7)) * 16)));
                sc[c] = __builtin_amdgcn_mfma_f32_16x16x32_bf16(qf[st], kf, sc[c], 0, 0, 0);
            }

        // scale + causal mask (diagonal tile only) + online softmax
        bool needmask = (kv0 + 63 > qw0);
        float pvv[4][4], tm[4];
        #pragma unroll
        for (int r = 0; r < 4; ++r) tm[r] = -3e38f;
        #pragma unroll
        for (int c = 0; c < 4; ++c) {
            int col = kv0 + c * 16 + cl;
            #pragma unroll
            for (int r = 0; r < 4; ++r) {
                int qrow = qw0 + g * 4 + r;
                float sval = sc[c][r] * SCALE_INV;
                if (needmask) sval = (col <= qrow) ? sval : -3e38f;
                pvv[c][r] = sval;
                tm[r] = fmaxf(tm[r], sval);
            }
        }
        #pragma unroll
        for (int m = 1; m <= 8; m <<= 1)
            #pragma unroll
            for (int r = 0; r < 4; ++r) tm[r] = fmaxf(tm[r], __shfl_xor(tm[r], m));
        float alpha[4], rs[4];
        #pragma unroll
        for (int r = 0; r < 4; ++r) {
            float mn = fmaxf(mrun[r], tm[r]);
            alpha[r] = __expf(mrun[r] - mn);
            mrun[r] = mn;
            rs[r] = 0.f;
        }
        #pragma unroll
        for (int c = 0; c < 4; ++c)
            #pragma unroll
            for (int r = 0; r < 4; ++r) {
                float p = __expf(pvv[c][r] - mrun[r]);
                pvv[c][r] = p;
                rs[r] += p;
            }
        #pragma unroll
        for (int m = 1; m <= 8; m <<= 1)
            #pragma unroll
            for (int r = 0; r < 4; ++r) rs[r] += __shfl_xor(rs[r], m);
        #pragma unroll
        for (int r = 0; r < 4; ++r) lsum[r] = lsum[r] * alpha[r] + rs[r];
        #pragma unroll
        for (int n = 0; n < 8; ++n)
            #pragma unroll
            for (int r = 0; r < 4; ++r) acc[n][r] *= alpha[r];

        // write P (bf16) to per-wave LDS, transposed-readable
        #pragma unroll
        for (int c = 0; c < 4; ++c)
            #pragma unroll
            for (int r = 0; r < 4; ++r)
                pt[w][(g * 4 + r) * 72 + c * 16 + cl] = f2bf(pvv[c][r]);

        // PV
        bf16x8 pa[2];
        #pragma unroll
        for (int ks = 0; ks < 2; ++ks)
            pa[ks] = as_bf(*(const u16x8*)((char*)&pt[w][0] + cl * 144 + ks * 64 + g * 16));
        #pragma unroll
        for (int n = 0; n < 8; ++n)
            #pragma unroll
            for (int ks = 0; ks < 2; ++ks) {
                int e = n * 16 + cl;
                bf16x8 vf = as_bf(*(const u16x8*)((char*)vt + e * 128 + (((ks * 4 + g) ^ (e & 7)) * 16)));
                acc[n] = __builtin_amdgcn_mfma_f32_16x16x32_bf16(pa[ks], vf, acc[n], 0, 0, 0);
            }

        if (!more) break;
        __syncthreads();                    // all reads of LDS done
        store_tile();                       // write prefetched tile
    }

    float inv[4];
    #pragma unroll
    for (int r = 0; r < 4; ++r) inv[r] = 1.0f / lsum[r];
    #pragma unroll
    for (int n = 0; n < 8; ++n)
        #pragma unroll
        for (int r = 0; r < 4; ++r) {
            int q = qw0 + g * 4 + r;
            Zg[(hs + q) * DH + n * 16 + cl] = f2bf(acc[n][r] * inv[r]);
        }
}

// ---------------------------------------------------------------------------
// 6) output GEMM (2-phase dbuf): z[16][2048][128] x Wot[2048][2048] (B^T) + bO
__global__ __launch_bounds__(256) void gemm_out(const u16* __restrict__ Z,
                                                const u16* __restrict__ Wot,
                                                const float* __restrict__ bO,
                                                float* __restrict__ out) {
    __shared__ u16 As[2 * 128 * 32], Bs[2 * 128 * 32];
    int m0 = blockIdx.x * 128, n0 = blockIdx.y * 128;
    int t = threadIdx.x, lane = t & 63, w = t >> 6;
    int wr = w >> 1, wc = w & 1;
    int cl = lane & 15, g = lane >> 4;
    int swz = (cl >> 1) & 3;

    auto stage = [&](int buf, int k0) {
        u16* Ab = As + buf * (128 * 32);
        u16* Bb = Bs + buf * (128 * 32);
        int hh = k0 >> 7, e0 = k0 & 127;
        #pragma unroll
        for (int j = 0; j < 2; ++j) {
            int idx = t + j * 256;
            int row = idx >> 2, slot = idx & 3;
            int slotS = slot ^ ((row >> 1) & 3);
            gload16(Z + ((size_t)hh * SEQ + m0 + row) * DH + e0 + slotS * 8, Ab + idx * 8);
            gload16(Wot + (size_t)(n0 + row) * DM + k0 + slotS * 8, Bb + idx * 8);
        }
    };

    f32x4 acc[4][4] = {};
    stage(0, 0);
    int cur = 0;
    for (int k0 = 0; k0 < DM; k0 += 32) {
        bool more = (k0 + 32 < DM);
        if (more) {
            stage(cur ^ 1, k0 + 32);
            VMCNT(4);
        } else {
            VMCNT(0);
        }
        SCHEDBAR;
        BARRIER;
        const u16* Ac = As + cur * (128 * 32);
        const u16* Bc = Bs + cur * (128 * 32);
        bf16x8 af[4], bfr[4];
        #pragma unroll
        for (int i = 0; i < 4; ++i)
            af[i] = as_bf(*(const u16x8*)&Ac[(wr*64 + i*16 + cl) * 32 + (g ^ swz) * 8]);
        #pragma unroll
        for (int j = 0; j < 4; ++j)
            bfr[j] = as_bf(*(const u16x8*)&Bc[(wc*64 + j*16 + cl) * 32 + (g ^ swz) * 8]);
        #pragma unroll
        for (int i = 0; i < 4; ++i)
            #pragma unroll
            for (int j = 0; j < 4; ++j)
                acc[i][j] = __builtin_amdgcn_mfma_f32_16x16x32_bf16(af[i], bfr[j], acc[i][j], 0, 0, 0);
        LGKMCNT0;
        SCHEDBAR;
        BARRIER;
        cur ^= 1;
    }
    #pragma unroll
    for (int i = 0; i < 4; ++i)
        #pragma unroll
        for (int j = 0; j < 4; ++j) {
            int col = n0 + wc * 64 + j * 16 + cl;
            float bb = bO[col];
            #pragma unroll
            for (int r = 0; r < 4; ++r) {
                int p = m0 + wr * 64 + i * 16 + g * 4 + r;
                out[(size_t)p * DM + col] = acc[i][j][r] + bb;
            }
        }
}

// ---------------------------------------------------------------------------
extern "C" void kernel_launch(void* const* d_in, const int* in_sizes, int n_in,
                              void* d_out, int out_size, void* d_ws, size_t ws_size,
                              hipStream_t stream) {
    const float* resid = (const float*)d_in[0];
    const float* WQ = (const float*)d_in[1];
    const float* WK = (const float*)d_in[2];
    const float* WV = (const float*)d_in[3];
    const float* WO = (const float*)d_in[4];
    const float* bQ = (const float*)d_in[5];
    const float* bK = (const float*)d_in[6];
    const float* bV = (const float*)d_in[7];
    const float* bO = (const float*)d_in[8];
    float* out = (float*)d_out;
    char* ws = (char*)d_ws;

    float2* rope = (float2*)(ws);                        // 1 MB
    u16* xn   = (u16*)(ws + (1ll  << 20));               // 8 MB
    u16* Wt   = (u16*)(ws + (9ll  << 20));               // 24 MB  [3][16][128][2048]
    u16* Wot  = (u16*)(ws + (33ll << 20));               // 8 MB   [2048][2048]
    u16* qkv  = (u16*)(ws + (41ll << 20));               // 24 MB  [q][k][vT]
    u16* z    = (u16*)(ws + (65ll << 20));               // 8 MB   [16][2048][128]

    rope_kernel<<<SEQ, 64, 0, stream>>>(rope);
    ln_kernel<<<SEQ, 256, 0, stream>>>(resid, xn);

    transpose_qkv<<<dim3(2, 32, 48), 256, 0, stream>>>(WQ, WK, WV, Wt);
    transpose_wo<<<dim3(32, 32, 1), 256, 0, stream>>>(WO, Wot);

    gemm_qkv<<<192, 512, 0, stream>>>(xn, Wt, bQ, bK, bV, rope, qkv);

    const u16* Qg = qkv;
    const u16* Kg = qkv + 1ll * NH * SEQ * DH;
    const u16* Vt = qkv + 2ll * NH * SEQ * DH;
    flash_kernel<<<dim3(NH, SEQ / 64), 256, 0, stream>>>(Qg, Kg, Vt, z);

    gemm_out<<<dim3(16, 16), 256, 0, stream>>>(z, Wot, bO, out);
}

// Round 6
// 203.323 us; speedup vs baseline: 1.7128x; 1.0344x over previous
//
#include <hip/hip_runtime.h>
#include <hip/hip_bf16.h>

// ---------------------------------------------------------------------------
// Problem constants (BATCH=1)
#define SEQ    2048
#define DM     2048
#define NH     16
#define DH     128
#define EPS    1e-5f
#define SCALE_INV 0.08838834764831845f   // 1/sqrt(128)
#define SC2LOG    0.12751744995f         // (1/sqrt(128)) * log2(e)

typedef unsigned short u16;
typedef u16  u16x4  __attribute__((ext_vector_type(4)));
typedef u16  u16x8  __attribute__((ext_vector_type(8)));
typedef __bf16 bf16x8 __attribute__((ext_vector_type(8)));
typedef float f32x4 __attribute__((ext_vector_type(4)));

__device__ __forceinline__ u16 f2bf(float f) {
    unsigned int u = __builtin_bit_cast(unsigned int, f);
    u += 0x7fffu + ((u >> 16) & 1u);      // RNE
    return (u16)(u >> 16);
}
__device__ __forceinline__ bf16x8 as_bf(u16x8 v) { return __builtin_bit_cast(bf16x8, v); }

// async global->LDS, 16B per lane.  LDS dest must be wave-uniform base + lane*16.
__device__ __forceinline__ void gload16(const u16* g, u16* l) {
    __builtin_amdgcn_global_load_lds(
        (const __attribute__((address_space(1))) unsigned int*)g,
        (__attribute__((address_space(3))) unsigned int*)l, 16, 0, 0);
}

#define VMCNT(N) asm volatile("s_waitcnt vmcnt(" #N ")" ::: "memory")
#define LGKMCNT0 asm volatile("s_waitcnt lgkmcnt(0)" ::: "memory")
#define SCHEDBAR __builtin_amdgcn_sched_barrier(0)
#define BARRIER  __builtin_amdgcn_s_barrier()

// ---------------------------------------------------------------------------
// 1) rotary table: tab[pos][i] = {sin(pos/10000^(i/64)), cos(...)}, i=0..63
__global__ void rope_kernel(float2* __restrict__ tab) {
    int i = threadIdx.x;                 // 0..63
    int pos = blockIdx.x;                // 0..2047
    float freq = powf(10000.f, (float)i * (1.f / 64.f));
    float ang = (float)pos / freq;
    tab[pos * 64 + i] = make_float2(sinf(ang), cosf(ang));
}

// ---------------------------------------------------------------------------
// 2) LayerNorm (center + rms of centered) fp32 -> bf16
__global__ __launch_bounds__(256) void ln_kernel(const float* __restrict__ x,
                                                 u16* __restrict__ xn) {
    int row = blockIdx.x, t = threadIdx.x;
    const float* xr = x + (size_t)row * DM;
    float4 v0 = *(const float4*)(xr + t * 4);
    float4 v1 = *(const float4*)(xr + 1024 + t * 4);
    float s = v0.x + v0.y + v0.z + v0.w + v1.x + v1.y + v1.z + v1.w;
    float q = v0.x*v0.x + v0.y*v0.y + v0.z*v0.z + v0.w*v0.w
            + v1.x*v1.x + v1.y*v1.y + v1.z*v1.z + v1.w*v1.w;
    #pragma unroll
    for (int o = 32; o; o >>= 1) { s += __shfl_xor(s, o); q += __shfl_xor(q, o); }
    __shared__ float ss[4], qq[4];
    if ((t & 63) == 0) { ss[t >> 6] = s; qq[t >> 6] = q; }
    __syncthreads();
    s = ss[0] + ss[1] + ss[2] + ss[3];
    q = qq[0] + qq[1] + qq[2] + qq[3];
    float mean = s * (1.f / DM);
    float var  = q * (1.f / DM) - mean * mean;
    float rstd = rsqrtf(var + EPS);
    u16* orow = xn + (size_t)row * DM;
    u16x4 o0 = { f2bf((v0.x-mean)*rstd), f2bf((v0.y-mean)*rstd),
                 f2bf((v0.z-mean)*rstd), f2bf((v0.w-mean)*rstd) };
    u16x4 o1 = { f2bf((v1.x-mean)*rstd), f2bf((v1.y-mean)*rstd),
                 f2bf((v1.z-mean)*rstd), f2bf((v1.w-mean)*rstd) };
    *(u16x4*)(orow + t * 4) = o0;
    *(u16x4*)(orow + 1024 + t * 4) = o1;
}

// ---------------------------------------------------------------------------
// 3a) combined QKV weight transpose + cvt: out[z][c][r] = W[z](r,c), z=which*16+h
__global__ __launch_bounds__(256) void transpose_qkv(const float* __restrict__ WQ,
                                                     const float* __restrict__ WK,
                                                     const float* __restrict__ WV,
                                                     u16* __restrict__ out) {
    int z = blockIdx.z, which = z >> 4, h = z & 15;
    const float* in = ((which == 0) ? WQ : (which == 1) ? WK : WV) + (size_t)h * DM * DH;
    u16* o = out + (size_t)z * DM * DH;
    int r0 = blockIdx.y * 64, c0 = blockIdx.x * 64;
    __shared__ u16 tile[64][65];
    int t = threadIdx.x;
    #pragma unroll
    for (int it = 0; it < 4; ++it) {
        int idx = t + it * 256;
        int rr = idx >> 4, cc = (idx & 15) * 4;
        float4 v = *(const float4*)(in + (size_t)(r0 + rr) * DH + c0 + cc);
        tile[rr][cc+0] = f2bf(v.x); tile[rr][cc+1] = f2bf(v.y);
        tile[rr][cc+2] = f2bf(v.z); tile[rr][cc+3] = f2bf(v.w);
    }
    __syncthreads();
    #pragma unroll
    for (int it = 0; it < 4; ++it) {
        int idx = t + it * 256;
        int oc = idx >> 4, orr = (idx & 15) * 4;
        u16x4 w = { tile[orr+0][oc], tile[orr+1][oc], tile[orr+2][oc], tile[orr+3][oc] };
        *(u16x4*)(o + (size_t)(c0 + oc) * DM + r0 + orr) = w;
    }
}

// 3b) WO transpose: out[c][r] = in[r][c], 2048x2048
__global__ __launch_bounds__(256) void transpose_wo(const float* __restrict__ in,
                                                    u16* __restrict__ out) {
    int r0 = blockIdx.y * 64, c0 = blockIdx.x * 64;
    __shared__ u16 tile[64][65];
    int t = threadIdx.x;
    #pragma unroll
    for (int it = 0; it < 4; ++it) {
        int idx = t + it * 256;
        int rr = idx >> 4, cc = (idx & 15) * 4;
        float4 v = *(const float4*)(in + (size_t)(r0 + rr) * DM + c0 + cc);
        tile[rr][cc+0] = f2bf(v.x); tile[rr][cc+1] = f2bf(v.y);
        tile[rr][cc+2] = f2bf(v.z); tile[rr][cc+3] = f2bf(v.w);
    }
    __syncthreads();
    #pragma unroll
    for (int it = 0; it < 4; ++it) {
        int idx = t + it * 256;
        int oc = idx >> 4, orr = (idx & 15) * 4;
        u16x4 w = { tile[orr+0][oc], tile[orr+1][oc], tile[orr+2][oc], tile[orr+3][oc] };
        *(u16x4*)(out + (size_t)(c0 + oc) * DM + r0 + orr) = w;
    }
}

// ---------------------------------------------------------------------------
// 4) QKV GEMM, 256x256 tile, BK=64, 8 waves (2x4), dbuf LDS + counted pipeline.
//    Xn[2048][2048] x Wt[6144][2048] (B^T rows = output cols) -> q/k/vT
__global__ __launch_bounds__(512, 2) void gemm_qkv(const u16* __restrict__ Xn,
                                                   const u16* __restrict__ Wt,
                                                   const float* __restrict__ bQ,
                                                   const float* __restrict__ bK,
                                                   const float* __restrict__ bV,
                                                   const float2* __restrict__ rope,
                                                   u16* __restrict__ qkv) {
    __shared__ u16 As[2][256 * 64], Bs[2][256 * 64];      // 128 KB total
    // T1: bijective XCD swizzle, 192 blocks / 8 XCDs = 24 per chunk
    int id = blockIdx.x;
    int swz = (id & 7) * 24 + (id >> 3);
    int bx = swz & 7, by = swz >> 3;                       // bx: M-tile, by: N-tile
    int m0 = bx * 256, n0 = by * 256;

    int t = threadIdx.x, lane = t & 63, wid = t >> 6;
    int wr = wid >> 2, wc = wid & 3;                       // 2 x 4 wave grid
    int cl = lane & 15, g = lane >> 4;

    auto stage = [&](int buf, int kt) {
        const u16* xa = Xn + (size_t)kt * 64;
        const u16* xb = Wt + (size_t)kt * 64;
        #pragma unroll
        for (int j = 0; j < 4; ++j) {
            int idx = t + j * 512;                 // 0..2047
            int row = idx >> 3;                    // 0..255
            int slotS = (idx & 7) ^ (row & 7);     // inverse swizzle on SOURCE
            gload16(xa + (size_t)(m0 + row) * DM + slotS * 8, &As[buf][idx * 8]);
            gload16(xb + (size_t)(n0 + row) * DM + slotS * 8, &Bs[buf][idx * 8]);
        }
    };

    f32x4 acc[8][4] = {};
    stage(0, 0);
    VMCNT(0);
    BARRIER;

    for (int kt = 0; kt < 32; ++kt) {
        int p = kt & 1;
        bool more = (kt + 1 < 32);
        bf16x8 bfr[4][2], af[4][2];
        // B frags: rows wc*64 + nj*16 + cl  (read once per tile)
        #pragma unroll
        for (int nj = 0; nj < 4; ++nj)
            #pragma unroll
            for (int kk = 0; kk < 2; ++kk) {
                int row = wc * 64 + nj * 16 + cl;
                int s = (kk * 4 + g) ^ (row & 7);
                bfr[nj][kk] = as_bf(*(const u16x8*)&Bs[p][row * 64 + s * 8]);
            }
        // A frags, m-half 0
        #pragma unroll
        for (int mi = 0; mi < 4; ++mi)
            #pragma unroll
            for (int kk = 0; kk < 2; ++kk) {
                int row = wr * 128 + mi * 16 + cl;
                int s = (kk * 4 + g) ^ (row & 7);
                af[mi][kk] = as_bf(*(const u16x8*)&As[p][row * 64 + s * 8]);
            }
        if (more) stage(p ^ 1, kt + 1);            // issue next tile early
        __builtin_amdgcn_s_setprio(1);
        #pragma unroll
        for (int mi = 0; mi < 4; ++mi)
            #pragma unroll
            for (int nj = 0; nj < 4; ++nj)
                #pragma unroll
                for (int kk = 0; kk < 2; ++kk)
                    acc[mi][nj] = __builtin_amdgcn_mfma_f32_16x16x32_bf16(af[mi][kk], bfr[nj][kk], acc[mi][nj], 0, 0, 0);
        __builtin_amdgcn_s_setprio(0);
        // A frags, m-half 1 (reuse registers)
        #pragma unroll
        for (int mi = 0; mi < 4; ++mi)
            #pragma unroll
            for (int kk = 0; kk < 2; ++kk) {
                int row = wr * 128 + 64 + mi * 16 + cl;
                int s = (kk * 4 + g) ^ (row & 7);
                af[mi][kk] = as_bf(*(const u16x8*)&As[p][row * 64 + s * 8]);
            }
        __builtin_amdgcn_s_setprio(1);
        #pragma unroll
        for (int mi = 0; mi < 4; ++mi)
            #pragma unroll
            for (int nj = 0; nj < 4; ++nj)
                #pragma unroll
                for (int kk = 0; kk < 2; ++kk)
                    acc[4 + mi][nj] = __builtin_amdgcn_mfma_f32_16x16x32_bf16(af[mi][kk], bfr[nj][kk], acc[4 + mi][nj], 0, 0, 0);
        __builtin_amdgcn_s_setprio(0);
        VMCNT(0);                                  // next tile's loads (aged) done
        SCHEDBAR;
        BARRIER;                                   // buf p free; buf p^1 ready
    }

    // epilogue: cols n0 + wc*64 + nj*16 + cl span 2 heads of one 'which'
    int which = n0 >> 11;
    const float* bias = (which == 0) ? bQ : (which == 1) ? bK : bV;
    #pragma unroll
    for (int i = 0; i < 8; ++i)
        #pragma unroll
        for (int nj = 0; nj < 4; ++nj) {
            int eg = n0 + wc * 64 + nj * 16 + cl;       // global col in [0,6144)
            int h = (eg >> 7) & 15;
            int e = eg & 127;
            float bb = bias[h * DH + e];
            int p0 = m0 + wr * 128 + i * 16 + g * 4;
            if (which == 2) {
                u16* vbase = qkv + 2ll * NH * SEQ * DH + (size_t)h * DH * SEQ;
                u16x4 o = { f2bf(acc[i][nj][0] + bb), f2bf(acc[i][nj][1] + bb),
                            f2bf(acc[i][nj][2] + bb), f2bf(acc[i][nj][3] + bb) };
                *(u16x4*)(vbase + (size_t)e * SEQ + p0) = o;
            } else {
                u16* outbase = qkv + ((size_t)which * 16 + h) * SEQ * DH;
                #pragma unroll
                for (int r = 0; r < 4; ++r) {
                    int pp = p0 + r;
                    float v = acc[i][nj][r] + bb;
                    float pv = __shfl_xor(v, 1);
                    float2 sc2 = rope[pp * 64 + (e >> 1)];
                    v = (e & 1) ? (v * sc2.y + pv * sc2.x) : (v * sc2.y - pv * sc2.x);
                    outbase[(size_t)pp * DH + e] = f2bf(v);
                }
            }
        }
}

// ---------------------------------------------------------------------------
// 5) causal flash attention.  grid (NH, SEQ/64), biggest q-tiles first.
//    4 waves x 16 q-rows; swapped QK^T (S^T: col=q) -> per-lane scalar softmax,
//    defer-max (T13), packed-b64 P^T transpose through per-wave LDS.
__global__ __launch_bounds__(256) void flash_kernel(const u16* __restrict__ Qg,
                                                    const u16* __restrict__ Kg,
                                                    const u16* __restrict__ Vt,
                                                    u16* __restrict__ Zg) {
    __shared__ u16 kt[64 * 128];            // K tile, rows kv (256B), slot-swizzled
    __shared__ u16 vt[128 * 64];            // V^T tile, rows e (128B), slot-swizzled
    __shared__ unsigned pt32[4 * 16 * 32];  // per-wave packed P^T [wave][q=cl][32 u32], 8KB
    int h = blockIdx.x;
    int nQ = gridDim.y;
    int q0 = (nQ - 1 - blockIdx.y) * 64;    // biggest first
    int t = threadIdx.x, lane = t & 63, w = t >> 6;
    int cl = lane & 15, g = lane >> 4;
    int qw0 = q0 + w * 16;
    const size_t hs = (size_t)h * SEQ;
    unsigned* ptw = pt32 + w * (16 * 32) + cl * 32;
    int swv = (cl & 7) << 1;                // unit swizzle (row-determined)

    // Q fragments (rotary already applied); used as the B-operand of mfma(K,Q)
    bf16x8 qf[4];
    #pragma unroll
    for (int st = 0; st < 4; ++st)
        qf[st] = as_bf(*(const u16x8*)(Qg + (hs + qw0 + cl) * DH + st * 32 + g * 8));

    f32x4 acc[8] = {};
    float mrun = -3e38f, lsum = 0.f;        // per-lane scalar state for q = qw0+cl

    u16x8 kreg[4], vreg[4];
    auto load_tile = [&](int kv0) {
        #pragma unroll
        for (int j = 0; j < 4; ++j) {
            int idx = t + j * 256;
            kreg[j] = *(const u16x8*)(Kg + (hs + kv0 + (idx >> 4)) * DH + (idx & 15) * 8);
            vreg[j] = *(const u16x8*)(Vt + ((size_t)h * DH + (idx >> 3)) * SEQ + kv0 + (idx & 7) * 8);
        }
    };
    auto store_tile = [&]() {
        #pragma unroll
        for (int j = 0; j < 4; ++j) {
            int idx = t + j * 256;
            int row = idx >> 4, slot = idx & 15;
            *(u16x8*)((char*)kt + row * 256 + ((slot ^ (row & 7)) * 16)) = kreg[j];
            int e = idx >> 3, ch = idx & 7;
            *(u16x8*)((char*)vt + e * 128 + ((ch ^ (e & 7)) * 16)) = vreg[j];
        }
    };

    load_tile(0);
    store_tile();

    for (int kv0 = 0; kv0 <= q0; kv0 += 64) {
        __syncthreads();                    // LDS tile ready
        bool more = (kv0 + 64 <= q0);
        if (more) load_tile(kv0 + 64);      // async prefetch into regs

        // S^T = K Q^T: col = q = cl, row = kv = c*16 + g*4 + r
        f32x4 sc[4] = {};
        #pragma unroll
        for (int st = 0; st < 4; ++st)
            #pragma unroll
            for (int c = 0; c < 4; ++c) {
                int row = c * 16 + cl;
                bf16x8 kf = as_bf(*(const u16x8*)((char*)kt + row * 256 + (((st * 4 + g) ^ (row & 7)) * 16)));
                sc[c] = __builtin_amdgcn_mfma_f32_16x16x32_bf16(kf, qf[st], sc[c], 0, 0, 0);
            }

        // scale (base-2) + causal mask + per-lane softmax
        bool needmask = (kv0 + 63 > qw0);
        int qrow = qw0 + cl;
        float pf[4][4];
        float tm = -3e38f;
        #pragma unroll
        for (int c = 0; c < 4; ++c)
            #pragma unroll
            for (int r = 0; r < 4; ++r) {
                int kvq = kv0 + c * 16 + g * 4 + r;
                float sval = sc[c][r] * SC2LOG;
                if (needmask) sval = (kvq <= qrow) ? sval : -3e38f;
                pf[c][r] = sval;
                tm = fmaxf(tm, sval);
            }
        tm = fmaxf(tm, __shfl_xor(tm, 16));
        tm = fmaxf(tm, __shfl_xor(tm, 32));

        if (!__all(tm <= mrun + 12.f)) {    // T13 defer-max: rescale only on growth
            float mn = fmaxf(mrun, tm);
            float alpha = exp2f(mrun - mn);
            mrun = mn;
            lsum *= alpha;
            float aR[4];
            #pragma unroll
            for (int r = 0; r < 4; ++r) aR[r] = __shfl(alpha, g * 4 + r);
            #pragma unroll
            for (int n = 0; n < 8; ++n)
                #pragma unroll
                for (int r = 0; r < 4; ++r) acc[n][r] *= aR[r];
        }
        float rs = 0.f;
        #pragma unroll
        for (int c = 0; c < 4; ++c)
            #pragma unroll
            for (int r = 0; r < 4; ++r) {
                float e2 = exp2f(pf[c][r] - mrun);
                pf[c][r] = e2;
                rs += e2;
            }
        rs += __shfl_xor(rs, 16);
        rs += __shfl_xor(rs, 32);
        lsum += rs;

        // pack P^T (bf16 pairs) into per-wave LDS: 4x ds_write_b64
        #pragma unroll
        for (int c = 0; c < 4; ++c) {
            unsigned lo = (unsigned)f2bf(pf[c][0]) | ((unsigned)f2bf(pf[c][1]) << 16);
            unsigned hi = (unsigned)f2bf(pf[c][2]) | ((unsigned)f2bf(pf[c][3]) << 16);
            int u = (c * 4 + g) ^ swv;
            *(unsigned long long*)(ptw + u * 2) =
                (unsigned long long)lo | ((unsigned long long)hi << 32);
        }
        // read A-frags for PV: 2x ds_read_b128 (row = own cl, same swizzle)
        bf16x8 pa[2];
        #pragma unroll
        for (int ks = 0; ks < 2; ++ks)
            pa[ks] = as_bf(*(const u16x8*)(ptw + ((ks * 8 + g * 2) ^ swv) * 2));

        // PV: O rows q = g*4+r, cols e = n*16+cl (unchanged)
        #pragma unroll
        for (int n = 0; n < 8; ++n)
            #pragma unroll
            for (int ks = 0; ks < 2; ++ks) {
                int e = n * 16 + cl;
                bf16x8 vf = as_bf(*(const u16x8*)((char*)vt + e * 128 + (((ks * 4 + g) ^ (e & 7)) * 16)));
                acc[n] = __builtin_amdgcn_mfma_f32_16x16x32_bf16(pa[ks], vf, acc[n], 0, 0, 0);
            }

        if (!more) break;
        __syncthreads();                    // all reads of LDS done
        store_tile();                       // write prefetched tile
    }

    float inv = 1.0f / lsum;
    float invR[4];
    #pragma unroll
    for (int r = 0; r < 4; ++r) invR[r] = __shfl(inv, g * 4 + r);
    #pragma unroll
    for (int n = 0; n < 8; ++n)
        #pragma unroll
        for (int r = 0; r < 4; ++r) {
            int q = qw0 + g * 4 + r;
            Zg[(hs + q) * DH + n * 16 + cl] = f2bf(acc[n][r] * invR[r]);
        }
}

// ---------------------------------------------------------------------------
// 6) output GEMM (2-phase dbuf): z[16][2048][128] x Wot[2048][2048] (B^T) + bO
__global__ __launch_bounds__(256) void gemm_out(const u16* __restrict__ Z,
                                                const u16* __restrict__ Wot,
                                                const float* __restrict__ bO,
                                                float* __restrict__ out) {
    __shared__ u16 As[2 * 128 * 32], Bs[2 * 128 * 32];
    int m0 = blockIdx.x * 128, n0 = blockIdx.y * 128;
    int t = threadIdx.x, lane = t & 63, w = t >> 6;
    int wr = w >> 1, wc = w & 1;
    int cl = lane & 15, g = lane >> 4;
    int swz = (cl >> 1) & 3;

    auto stage = [&](int buf, int k0) {
        u16* Ab = As + buf * (128 * 32);
        u16* Bb = Bs + buf * (128 * 32);
        int hh = k0 >> 7, e0 = k0 & 127;
        #pragma unroll
        for (int j = 0; j < 2; ++j) {
            int idx = t + j * 256;
            int row = idx >> 2, slot = idx & 3;
            int slotS = slot ^ ((row >> 1) & 3);
            gload16(Z + ((size_t)hh * SEQ + m0 + row) * DH + e0 + slotS * 8, Ab + idx * 8);
            gload16(Wot + (size_t)(n0 + row) * DM + k0 + slotS * 8, Bb + idx * 8);
        }
    };

    f32x4 acc[4][4] = {};
    stage(0, 0);
    int cur = 0;
    for (int k0 = 0; k0 < DM; k0 += 32) {
        bool more = (k0 + 32 < DM);
        if (more) {
            stage(cur ^ 1, k0 + 32);
            VMCNT(4);
        } else {
            VMCNT(0);
        }
        SCHEDBAR;
        BARRIER;
        const u16* Ac = As + cur * (128 * 32);
        const u16* Bc = Bs + cur * (128 * 32);
        bf16x8 af[4], bfr[4];
        #pragma unroll
        for (int i = 0; i < 4; ++i)
            af[i] = as_bf(*(const u16x8*)&Ac[(wr*64 + i*16 + cl) * 32 + (g ^ swz) * 8]);
        #pragma unroll
        for (int j = 0; j < 4; ++j)
            bfr[j] = as_bf(*(const u16x8*)&Bc[(wc*64 + j*16 + cl) * 32 + (g ^ swz) * 8]);
        #pragma unroll
        for (int i = 0; i < 4; ++i)
            #pragma unroll
            for (int j = 0; j < 4; ++j)
                acc[i][j] = __builtin_amdgcn_mfma_f32_16x16x32_bf16(af[i], bfr[j], acc[i][j], 0, 0, 0);
        LGKMCNT0;
        SCHEDBAR;
        BARRIER;
        cur ^= 1;
    }
    #pragma unroll
    for (int i = 0; i < 4; ++i)
        #pragma unroll
        for (int j = 0; j < 4; ++j) {
            int col = n0 + wc * 64 + j * 16 + cl;
            float bb = bO[col];
            #pragma unroll
            for (int r = 0; r < 4; ++r) {
                int p = m0 + wr * 64 + i * 16 + g * 4 + r;
                out[(size_t)p * DM + col] = acc[i][j][r] + bb;
            }
        }
}

// ---------------------------------------------------------------------------
extern "C" void kernel_launch(void* const* d_in, const int* in_sizes, int n_in,
                              void* d_out, int out_size, void* d_ws, size_t ws_size,
                              hipStream_t stream) {
    const float* resid = (const float*)d_in[0];
    const float* WQ = (const float*)d_in[1];
    const float* WK = (const float*)d_in[2];
    const float* WV = (const float*)d_in[3];
    const float* WO = (const float*)d_in[4];
    const float* bQ = (const float*)d_in[5];
    const float* bK = (const float*)d_in[6];
    const float* bV = (const float*)d_in[7];
    const float* bO = (const float*)d_in[8];
    float* out = (float*)d_out;
    char* ws = (char*)d_ws;

    float2* rope = (float2*)(ws);                        // 1 MB
    u16* xn   = (u16*)(ws + (1ll  << 20));               // 8 MB
    u16* Wt   = (u16*)(ws + (9ll  << 20));               // 24 MB  [3][16][128][2048]
    u16* Wot  = (u16*)(ws + (33ll << 20));               // 8 MB   [2048][2048]
    u16* qkv  = (u16*)(ws + (41ll << 20));               // 24 MB  [q][k][vT]
    u16* z    = (u16*)(ws + (65ll << 20));               // 8 MB   [16][2048][128]

    rope_kernel<<<SEQ, 64, 0, stream>>>(rope);
    ln_kernel<<<SEQ, 256, 0, stream>>>(resid, xn);

    transpose_qkv<<<dim3(2, 32, 48), 256, 0, stream>>>(WQ, WK, WV, Wt);
    transpose_wo<<<dim3(32, 32, 1), 256, 0, stream>>>(WO, Wot);

    gemm_qkv<<<192, 512, 0, stream>>>(xn, Wt, bQ, bK, bV, rope, qkv);

    const u16* Qg = qkv;
    const u16* Kg = qkv + 1ll * NH * SEQ * DH;
    const u16* Vt = qkv + 2ll * NH * SEQ * DH;
    flash_kernel<<<dim3(NH, SEQ / 64), 256, 0, stream>>>(Qg, Kg, Vt, z);

    gemm_out<<<dim3(16, 16), 256, 0, stream>>>(z, Wot, bO, out);
}

// Round 7
// 200.971 us; speedup vs baseline: 1.7329x; 1.0117x over previous
//
#include <hip/hip_runtime.h>
#include <hip/hip_bf16.h>

// ---------------------------------------------------------------------------
// Problem constants (BATCH=1)
#define SEQ    2048
#define DM     2048
#define NH     16
#define DH     128
#define EPS    1e-5f
#define SCALE_INV 0.08838834764831845f   // 1/sqrt(128)
#define SC2LOG    0.12751744995f         // (1/sqrt(128)) * log2(e)

typedef unsigned short u16;
typedef u16  u16x4  __attribute__((ext_vector_type(4)));
typedef u16  u16x8  __attribute__((ext_vector_type(8)));
typedef __bf16 bf16x8 __attribute__((ext_vector_type(8)));
typedef float f32x4 __attribute__((ext_vector_type(4)));

__device__ __forceinline__ u16 f2bf(float f) {
    unsigned int u = __builtin_bit_cast(unsigned int, f);
    u += 0x7fffu + ((u >> 16) & 1u);      // RNE
    return (u16)(u >> 16);
}
__device__ __forceinline__ float bf2f(u16 v) {
    return __builtin_bit_cast(float, (unsigned)v << 16);
}
__device__ __forceinline__ bf16x8 as_bf(u16x8 v) { return __builtin_bit_cast(bf16x8, v); }

// async global->LDS, 16B per lane.  LDS dest must be wave-uniform base + lane*16.
__device__ __forceinline__ void gload16(const u16* g, u16* l) {
    __builtin_amdgcn_global_load_lds(
        (const __attribute__((address_space(1))) unsigned int*)g,
        (__attribute__((address_space(3))) unsigned int*)l, 16, 0, 0);
}

#define VMCNT(N) asm volatile("s_waitcnt vmcnt(" #N ")" ::: "memory")
#define LGKMCNT0 asm volatile("s_waitcnt lgkmcnt(0)" ::: "memory")
#define SCHEDBAR __builtin_amdgcn_sched_barrier(0)
#define BARRIER  __builtin_amdgcn_s_barrier()

// ---------------------------------------------------------------------------
// 1) rotary table: tab[pos][i] = {sin(pos/10000^(i/64)), cos(...)}, i=0..63
__global__ void rope_kernel(float2* __restrict__ tab) {
    int i = threadIdx.x;                 // 0..63
    int pos = blockIdx.x;                // 0..2047
    float freq = powf(10000.f, (float)i * (1.f / 64.f));
    float ang = (float)pos / freq;
    tab[pos * 64 + i] = make_float2(sinf(ang), cosf(ang));
}

// ---------------------------------------------------------------------------
// 2) LayerNorm (center + rms of centered) fp32 -> bf16
__global__ __launch_bounds__(256) void ln_kernel(const float* __restrict__ x,
                                                 u16* __restrict__ xn) {
    int row = blockIdx.x, t = threadIdx.x;
    const float* xr = x + (size_t)row * DM;
    float4 v0 = *(const float4*)(xr + t * 4);
    float4 v1 = *(const float4*)(xr + 1024 + t * 4);
    float s = v0.x + v0.y + v0.z + v0.w + v1.x + v1.y + v1.z + v1.w;
    float q = v0.x*v0.x + v0.y*v0.y + v0.z*v0.z + v0.w*v0.w
            + v1.x*v1.x + v1.y*v1.y + v1.z*v1.z + v1.w*v1.w;
    #pragma unroll
    for (int o = 32; o; o >>= 1) { s += __shfl_xor(s, o); q += __shfl_xor(q, o); }
    __shared__ float ss[4], qq[4];
    if ((t & 63) == 0) { ss[t >> 6] = s; qq[t >> 6] = q; }
    __syncthreads();
    s = ss[0] + ss[1] + ss[2] + ss[3];
    q = qq[0] + qq[1] + qq[2] + qq[3];
    float mean = s * (1.f / DM);
    float var  = q * (1.f / DM) - mean * mean;
    float rstd = rsqrtf(var + EPS);
    u16* orow = xn + (size_t)row * DM;
    u16x4 o0 = { f2bf((v0.x-mean)*rstd), f2bf((v0.y-mean)*rstd),
                 f2bf((v0.z-mean)*rstd), f2bf((v0.w-mean)*rstd) };
    u16x4 o1 = { f2bf((v1.x-mean)*rstd), f2bf((v1.y-mean)*rstd),
                 f2bf((v1.z-mean)*rstd), f2bf((v1.w-mean)*rstd) };
    *(u16x4*)(orow + t * 4) = o0;
    *(u16x4*)(orow + 1024 + t * 4) = o1;
}

// ---------------------------------------------------------------------------
// 3a) combined QKV weight transpose + cvt: out[z][c][r] = W[z](r,c), z=which*16+h
__global__ __launch_bounds__(256) void transpose_qkv(const float* __restrict__ WQ,
                                                     const float* __restrict__ WK,
                                                     const float* __restrict__ WV,
                                                     u16* __restrict__ out) {
    int z = blockIdx.z, which = z >> 4, h = z & 15;
    const float* in = ((which == 0) ? WQ : (which == 1) ? WK : WV) + (size_t)h * DM * DH;
    u16* o = out + (size_t)z * DM * DH;
    int r0 = blockIdx.y * 64, c0 = blockIdx.x * 64;
    __shared__ u16 tile[64][65];
    int t = threadIdx.x;
    #pragma unroll
    for (int it = 0; it < 4; ++it) {
        int idx = t + it * 256;
        int rr = idx >> 4, cc = (idx & 15) * 4;
        float4 v = *(const float4*)(in + (size_t)(r0 + rr) * DH + c0 + cc);
        tile[rr][cc+0] = f2bf(v.x); tile[rr][cc+1] = f2bf(v.y);
        tile[rr][cc+2] = f2bf(v.z); tile[rr][cc+3] = f2bf(v.w);
    }
    __syncthreads();
    #pragma unroll
    for (int it = 0; it < 4; ++it) {
        int idx = t + it * 256;
        int oc = idx >> 4, orr = (idx & 15) * 4;
        u16x4 w = { tile[orr+0][oc], tile[orr+1][oc], tile[orr+2][oc], tile[orr+3][oc] };
        *(u16x4*)(o + (size_t)(c0 + oc) * DM + r0 + orr) = w;
    }
}

// 3b) WO transpose: out[c][r] = in[r][c], 2048x2048
__global__ __launch_bounds__(256) void transpose_wo(const float* __restrict__ in,
                                                    u16* __restrict__ out) {
    int r0 = blockIdx.y * 64, c0 = blockIdx.x * 64;
    __shared__ u16 tile[64][65];
    int t = threadIdx.x;
    #pragma unroll
    for (int it = 0; it < 4; ++it) {
        int idx = t + it * 256;
        int rr = idx >> 4, cc = (idx & 15) * 4;
        float4 v = *(const float4*)(in + (size_t)(r0 + rr) * DM + c0 + cc);
        tile[rr][cc+0] = f2bf(v.x); tile[rr][cc+1] = f2bf(v.y);
        tile[rr][cc+2] = f2bf(v.z); tile[rr][cc+3] = f2bf(v.w);
    }
    __syncthreads();
    #pragma unroll
    for (int it = 0; it < 4; ++it) {
        int idx = t + it * 256;
        int oc = idx >> 4, orr = (idx & 15) * 4;
        u16x4 w = { tile[orr+0][oc], tile[orr+1][oc], tile[orr+2][oc], tile[orr+3][oc] };
        *(u16x4*)(out + (size_t)(c0 + oc) * DM + r0 + orr) = w;
    }
}

// ---------------------------------------------------------------------------
// 4) QKV GEMM, 256x256 tile, BK=64, 8 waves (2x4), dbuf LDS + counted pipeline.
__global__ __launch_bounds__(512, 2) void gemm_qkv(const u16* __restrict__ Xn,
                                                   const u16* __restrict__ Wt,
                                                   const float* __restrict__ bQ,
                                                   const float* __restrict__ bK,
                                                   const float* __restrict__ bV,
                                                   const float2* __restrict__ rope,
                                                   u16* __restrict__ qkv) {
    __shared__ u16 As[2][256 * 64], Bs[2][256 * 64];      // 128 KB total
    int id = blockIdx.x;
    int swz = (id & 7) * 24 + (id >> 3);
    int bx = swz & 7, by = swz >> 3;
    int m0 = bx * 256, n0 = by * 256;

    int t = threadIdx.x, lane = t & 63, wid = t >> 6;
    int wr = wid >> 2, wc = wid & 3;
    int cl = lane & 15, g = lane >> 4;

    auto stage = [&](int buf, int kt) {
        const u16* xa = Xn + (size_t)kt * 64;
        const u16* xb = Wt + (size_t)kt * 64;
        #pragma unroll
        for (int j = 0; j < 4; ++j) {
            int idx = t + j * 512;
            int row = idx >> 3;
            int slotS = (idx & 7) ^ (row & 7);
            gload16(xa + (size_t)(m0 + row) * DM + slotS * 8, &As[buf][idx * 8]);
            gload16(xb + (size_t)(n0 + row) * DM + slotS * 8, &Bs[buf][idx * 8]);
        }
    };

    f32x4 acc[8][4] = {};
    stage(0, 0);
    VMCNT(0);
    BARRIER;

    for (int kt = 0; kt < 32; ++kt) {
        int p = kt & 1;
        bool more = (kt + 1 < 32);
        bf16x8 bfr[4][2], af[4][2];
        #pragma unroll
        for (int nj = 0; nj < 4; ++nj)
            #pragma unroll
            for (int kk = 0; kk < 2; ++kk) {
                int row = wc * 64 + nj * 16 + cl;
                int s = (kk * 4 + g) ^ (row & 7);
                bfr[nj][kk] = as_bf(*(const u16x8*)&Bs[p][row * 64 + s * 8]);
            }
        #pragma unroll
        for (int mi = 0; mi < 4; ++mi)
            #pragma unroll
            for (int kk = 0; kk < 2; ++kk) {
                int row = wr * 128 + mi * 16 + cl;
                int s = (kk * 4 + g) ^ (row & 7);
                af[mi][kk] = as_bf(*(const u16x8*)&As[p][row * 64 + s * 8]);
            }
        if (more) stage(p ^ 1, kt + 1);
        __builtin_amdgcn_s_setprio(1);
        #pragma unroll
        for (int mi = 0; mi < 4; ++mi)
            #pragma unroll
            for (int nj = 0; nj < 4; ++nj)
                #pragma unroll
                for (int kk = 0; kk < 2; ++kk)
                    acc[mi][nj] = __builtin_amdgcn_mfma_f32_16x16x32_bf16(af[mi][kk], bfr[nj][kk], acc[mi][nj], 0, 0, 0);
        __builtin_amdgcn_s_setprio(0);
        #pragma unroll
        for (int mi = 0; mi < 4; ++mi)
            #pragma unroll
            for (int kk = 0; kk < 2; ++kk) {
                int row = wr * 128 + 64 + mi * 16 + cl;
                int s = (kk * 4 + g) ^ (row & 7);
                af[mi][kk] = as_bf(*(const u16x8*)&As[p][row * 64 + s * 8]);
            }
        __builtin_amdgcn_s_setprio(1);
        #pragma unroll
        for (int mi = 0; mi < 4; ++mi)
            #pragma unroll
            for (int nj = 0; nj < 4; ++nj)
                #pragma unroll
                for (int kk = 0; kk < 2; ++kk)
                    acc[4 + mi][nj] = __builtin_amdgcn_mfma_f32_16x16x32_bf16(af[mi][kk], bfr[nj][kk], acc[4 + mi][nj], 0, 0, 0);
        __builtin_amdgcn_s_setprio(0);
        VMCNT(0);
        SCHEDBAR;
        BARRIER;
    }

    int which = n0 >> 11;
    const float* bias = (which == 0) ? bQ : (which == 1) ? bK : bV;
    #pragma unroll
    for (int i = 0; i < 8; ++i)
        #pragma unroll
        for (int nj = 0; nj < 4; ++nj) {
            int eg = n0 + wc * 64 + nj * 16 + cl;
            int h = (eg >> 7) & 15;
            int e = eg & 127;
            float bb = bias[h * DH + e];
            int p0 = m0 + wr * 128 + i * 16 + g * 4;
            if (which == 2) {
                u16* vbase = qkv + 2ll * NH * SEQ * DH + (size_t)h * DH * SEQ;
                u16x4 o = { f2bf(acc[i][nj][0] + bb), f2bf(acc[i][nj][1] + bb),
                            f2bf(acc[i][nj][2] + bb), f2bf(acc[i][nj][3] + bb) };
                *(u16x4*)(vbase + (size_t)e * SEQ + p0) = o;
            } else {
                u16* outbase = qkv + ((size_t)which * 16 + h) * SEQ * DH;
                #pragma unroll
                for (int r = 0; r < 4; ++r) {
                    int pp = p0 + r;
                    float v = acc[i][nj][r] + bb;
                    float pv = __shfl_xor(v, 1);
                    float2 sc2 = rope[pp * 64 + (e >> 1)];
                    v = (e & 1) ? (v * sc2.y + pv * sc2.x) : (v * sc2.y - pv * sc2.x);
                    outbase[(size_t)pp * DH + e] = f2bf(v);
                }
            }
        }
}

// ---------------------------------------------------------------------------
// part prefix for multi-chunk q-tiles (j>=8): Sigma_{jj=8..j-1} (jj/8+1)
__device__ __forceinline__ int part_prefix(int j) {
    return (j < 16) ? 2 * (j - 8) : (j < 24 ? 16 + 3 * (j - 16) : 40 + 4 * (j - 24));
}

// ---------------------------------------------------------------------------
// 5) causal flash attention with KV-split.  grid (NH, 80): block = (h, j, c)
//    where q-tile j (64 rows) splits its j+1 KV-tiles into nc=ceil((j+1)/8)
//    chunks.  Single-chunk -> final Z; multi-chunk -> bf16 partial O + (m,l).
__global__ __launch_bounds__(256) void flash_kernel(const u16* __restrict__ Qg,
                                                    const u16* __restrict__ Kg,
                                                    const u16* __restrict__ Vt,
                                                    u16* __restrict__ Zg,
                                                    u16* __restrict__ pO,
                                                    float2* __restrict__ ml) {
    __shared__ u16 kt[64 * 128];            // K tile, rows kv (256B), slot-swizzled
    __shared__ u16 vt[128 * 64];            // V^T tile, rows e (128B), slot-swizzled
    __shared__ unsigned pt32[4 * 16 * 32];  // per-wave packed P^T, 8KB
    int h = blockIdx.x;
    // decode chunk: enumerate j descending (big chunks dispatch first)
    int rem = blockIdx.y;
    int j = 31, c = 0;
    #pragma unroll 1
    for (int jj = 31; jj >= 0; --jj) {
        int ncj = (jj >> 3) + 1;
        if (rem < ncj) { j = jj; c = rem; break; }
        rem -= ncj;
    }
    int q0 = j * 64;
    int nc = (j >> 3) + 1;
    bool multi = (nc > 1);
    int kt0 = c * 8;
    int kt1 = min(j, c * 8 + 7);

    int t = threadIdx.x, lane = t & 63, w = t >> 6;
    int cl = lane & 15, g = lane >> 4;
    int qw0 = q0 + w * 16;
    const size_t hs = (size_t)h * SEQ;
    unsigned* ptw = pt32 + w * (16 * 32) + cl * 32;
    int swv = (cl & 7) << 1;

    // Q fragments (rotary already applied); B-operand of mfma(K,Q)
    bf16x8 qf[4];
    #pragma unroll
    for (int st = 0; st < 4; ++st)
        qf[st] = as_bf(*(const u16x8*)(Qg + (hs + qw0 + cl) * DH + st * 32 + g * 8));

    f32x4 acc[8] = {};
    float mrun = -3e38f, lsum = 0.f;

    u16x8 kreg[4], vreg[4];
    auto load_tile = [&](int kv0) {
        #pragma unroll
        for (int jj = 0; jj < 4; ++jj) {
            int idx = t + jj * 256;
            kreg[jj] = *(const u16x8*)(Kg + (hs + kv0 + (idx >> 4)) * DH + (idx & 15) * 8);
            vreg[jj] = *(const u16x8*)(Vt + ((size_t)h * DH + (idx >> 3)) * SEQ + kv0 + (idx & 7) * 8);
        }
    };
    auto store_tile = [&]() {
        #pragma unroll
        for (int jj = 0; jj < 4; ++jj) {
            int idx = t + jj * 256;
            int row = idx >> 4, slot = idx & 15;
            *(u16x8*)((char*)kt + row * 256 + ((slot ^ (row & 7)) * 16)) = kreg[jj];
            int e = idx >> 3, ch = idx & 7;
            *(u16x8*)((char*)vt + e * 128 + ((ch ^ (e & 7)) * 16)) = vreg[jj];
        }
    };

    int kvbeg = kt0 * 64, kvend = kt1 * 64;
    load_tile(kvbeg);
    store_tile();

    for (int kv0 = kvbeg; kv0 <= kvend; kv0 += 64) {
        __syncthreads();
        bool more = (kv0 + 64 <= kvend);
        if (more) load_tile(kv0 + 64);

        // S^T = K Q^T: col = q = cl, row = kv = cc*16 + g*4 + r
        f32x4 sc[4] = {};
        __builtin_amdgcn_s_setprio(1);
        #pragma unroll
        for (int st = 0; st < 4; ++st)
            #pragma unroll
            for (int cc = 0; cc < 4; ++cc) {
                int row = cc * 16 + cl;
                bf16x8 kf = as_bf(*(const u16x8*)((char*)kt + row * 256 + (((st * 4 + g) ^ (row & 7)) * 16)));
                sc[cc] = __builtin_amdgcn_mfma_f32_16x16x32_bf16(kf, qf[st], sc[cc], 0, 0, 0);
            }
        __builtin_amdgcn_s_setprio(0);

        bool needmask = (kv0 + 63 > qw0);
        int qrow = qw0 + cl;
        float pf[4][4];
        float tm = -3e38f;
        #pragma unroll
        for (int cc = 0; cc < 4; ++cc)
            #pragma unroll
            for (int r = 0; r < 4; ++r) {
                int kvq = kv0 + cc * 16 + g * 4 + r;
                float sval = sc[cc][r] * SC2LOG;
                if (needmask) sval = (kvq <= qrow) ? sval : -3e38f;
                pf[cc][r] = sval;
                tm = fmaxf(tm, sval);
            }
        tm = fmaxf(tm, __shfl_xor(tm, 16));
        tm = fmaxf(tm, __shfl_xor(tm, 32));

        if (!__all(tm <= mrun + 12.f)) {
            float mn = fmaxf(mrun, tm);
            float alpha = exp2f(mrun - mn);
            mrun = mn;
            lsum *= alpha;
            float aR[4];
            #pragma unroll
            for (int r = 0; r < 4; ++r) aR[r] = __shfl(alpha, g * 4 + r);
            #pragma unroll
            for (int n = 0; n < 8; ++n)
                #pragma unroll
                for (int r = 0; r < 4; ++r) acc[n][r] *= aR[r];
        }
        float rs = 0.f;
        #pragma unroll
        for (int cc = 0; cc < 4; ++cc)
            #pragma unroll
            for (int r = 0; r < 4; ++r) {
                float e2 = exp2f(pf[cc][r] - mrun);
                pf[cc][r] = e2;
                rs += e2;
            }
        rs += __shfl_xor(rs, 16);
        rs += __shfl_xor(rs, 32);
        lsum += rs;

        // pack P^T (bf16 pairs) into per-wave LDS: 4x ds_write_b64
        #pragma unroll
        for (int cc = 0; cc < 4; ++cc) {
            unsigned lo = (unsigned)f2bf(pf[cc][0]) | ((unsigned)f2bf(pf[cc][1]) << 16);
            unsigned hi = (unsigned)f2bf(pf[cc][2]) | ((unsigned)f2bf(pf[cc][3]) << 16);
            int u = (cc * 4 + g) ^ swv;
            *(unsigned long long*)(ptw + u * 2) =
                (unsigned long long)lo | ((unsigned long long)hi << 32);
        }
        bf16x8 pa[2];
        #pragma unroll
        for (int ks = 0; ks < 2; ++ks)
            pa[ks] = as_bf(*(const u16x8*)(ptw + ((ks * 8 + g * 2) ^ swv) * 2));

        // PV
        __builtin_amdgcn_s_setprio(1);
        #pragma unroll
        for (int n = 0; n < 8; ++n)
            #pragma unroll
            for (int ks = 0; ks < 2; ++ks) {
                int e = n * 16 + cl;
                bf16x8 vf = as_bf(*(const u16x8*)((char*)vt + e * 128 + (((ks * 4 + g) ^ (e & 7)) * 16)));
                acc[n] = __builtin_amdgcn_mfma_f32_16x16x32_bf16(pa[ks], vf, acc[n], 0, 0, 0);
            }
        __builtin_amdgcn_s_setprio(0);

        if (!more) break;
        __syncthreads();
        store_tile();
    }

    if (multi) {
        int pidx = h * 72 + part_prefix(j) + c;
        if (lane < 16) ml[(size_t)pidx * 64 + w * 16 + cl] = make_float2(mrun, lsum);
        u16* po = pO + (size_t)pidx * (64 * 128);
        #pragma unroll
        for (int n = 0; n < 8; ++n)
            #pragma unroll
            for (int r = 0; r < 4; ++r)
                po[(w * 16 + g * 4 + r) * 128 + n * 16 + cl] = f2bf(acc[n][r]);
    } else {
        float inv = 1.0f / lsum;
        float invR[4];
        #pragma unroll
        for (int r = 0; r < 4; ++r) invR[r] = __shfl(inv, g * 4 + r);
        #pragma unroll
        for (int n = 0; n < 8; ++n)
            #pragma unroll
            for (int r = 0; r < 4; ++r) {
                int q = qw0 + g * 4 + r;
                Zg[(hs + q) * DH + n * 16 + cl] = f2bf(acc[n][r] * invR[r]);
            }
    }
}

// ---------------------------------------------------------------------------
// 5b) merge partial chunks: grid (NH, 24), j = blockIdx.y + 8
__global__ __launch_bounds__(256) void merge_kernel(const u16* __restrict__ pO,
                                                    const float2* __restrict__ ml,
                                                    u16* __restrict__ Zg) {
    int h = blockIdx.x;
    int j = blockIdx.y + 8;
    int nc = (j >> 3) + 1;                   // 2..4
    int pbase = h * 72 + part_prefix(j);
    int t = threadIdx.x;
    int row = t >> 2;                        // 0..63
    int c0 = (t & 3) * 32;

    float mv[4], lv[4];
    float M = -3e38f;
    #pragma unroll
    for (int i = 0; i < 4; ++i) {
        int ii = (i < nc) ? i : 0;
        float2 mli = ml[(size_t)(pbase + ii) * 64 + row];
        mv[i] = mli.x; lv[i] = mli.y;
        if (i < nc) M = fmaxf(M, mli.x);
    }
    float wgt[4];
    float L = 0.f;
    #pragma unroll
    for (int i = 0; i < 4; ++i) {
        wgt[i] = (i < nc) ? exp2f(mv[i] - M) : 0.f;
        L += wgt[i] * lv[i];
    }
    float invL = 1.f / L;

    #pragma unroll
    for (int ccc = 0; ccc < 32; ccc += 8) {
        float o[8] = {};
        #pragma unroll
        for (int i = 0; i < 4; ++i) {
            int ii = (i < nc) ? i : 0;
            u16x8 v = *(const u16x8*)(pO + ((size_t)(pbase + ii) * 64 + row) * 128 + c0 + ccc);
            #pragma unroll
            for (int k = 0; k < 8; ++k) o[k] += wgt[i] * bf2f(v[k]);
        }
        u16x8 zv;
        #pragma unroll
        for (int k = 0; k < 8; ++k) zv[k] = f2bf(o[k] * invL);
        *(u16x8*)(Zg + ((size_t)h * SEQ + j * 64 + row) * DH + c0 + ccc) = zv;
    }
}

// ---------------------------------------------------------------------------
// 6) output GEMM (2-phase dbuf): z[16][2048][128] x Wot[2048][2048] (B^T) + bO
__global__ __launch_bounds__(256) void gemm_out(const u16* __restrict__ Z,
                                                const u16* __restrict__ Wot,
                                                const float* __restrict__ bO,
                                                float* __restrict__ out) {
    __shared__ u16 As[2 * 128 * 32], Bs[2 * 128 * 32];
    int m0 = blockIdx.x * 128, n0 = blockIdx.y * 128;
    int t = threadIdx.x, lane = t & 63, w = t >> 6;
    int wr = w >> 1, wc = w & 1;
    int cl = lane & 15, g = lane >> 4;
    int swz = (cl >> 1) & 3;

    auto stage = [&](int buf, int k0) {
        u16* Ab = As + buf * (128 * 32);
        u16* Bb = Bs + buf * (128 * 32);
        int hh = k0 >> 7, e0 = k0 & 127;
        #pragma unroll
        for (int j = 0; j < 2; ++j) {
            int idx = t + j * 256;
            int row = idx >> 2, slot = idx & 3;
            int slotS = slot ^ ((row >> 1) & 3);
            gload16(Z + ((size_t)hh * SEQ + m0 + row) * DH + e0 + slotS * 8, Ab + idx * 8);
            gload16(Wot + (size_t)(n0 + row) * DM + k0 + slotS * 8, Bb + idx * 8);
        }
    };

    f32x4 acc[4][4] = {};
    stage(0, 0);
    int cur = 0;
    for (int k0 = 0; k0 < DM; k0 += 32) {
        bool more = (k0 + 32 < DM);
        if (more) {
            stage(cur ^ 1, k0 + 32);
            VMCNT(4);
        } else {
            VMCNT(0);
        }
        SCHEDBAR;
        BARRIER;
        const u16* Ac = As + cur * (128 * 32);
        const u16* Bc = Bs + cur * (128 * 32);
        bf16x8 af[4], bfr[4];
        #pragma unroll
        for (int i = 0; i < 4; ++i)
            af[i] = as_bf(*(const u16x8*)&Ac[(wr*64 + i*16 + cl) * 32 + (g ^ swz) * 8]);
        #pragma unroll
        for (int j = 0; j < 4; ++j)
            bfr[j] = as_bf(*(const u16x8*)&Bc[(wc*64 + j*16 + cl) * 32 + (g ^ swz) * 8]);
        #pragma unroll
        for (int i = 0; i < 4; ++i)
            #pragma unroll
            for (int j = 0; j < 4; ++j)
                acc[i][j] = __builtin_amdgcn_mfma_f32_16x16x32_bf16(af[i], bfr[j], acc[i][j], 0, 0, 0);
        LGKMCNT0;
        SCHEDBAR;
        BARRIER;
        cur ^= 1;
    }
    #pragma unroll
    for (int i = 0; i < 4; ++i)
        #pragma unroll
        for (int j = 0; j < 4; ++j) {
            int col = n0 + wc * 64 + j * 16 + cl;
            float bb = bO[col];
            #pragma unroll
            for (int r = 0; r < 4; ++r) {
                int p = m0 + wr * 64 + i * 16 + g * 4 + r;
                out[(size_t)p * DM + col] = acc[i][j][r] + bb;
            }
        }
}

// ---------------------------------------------------------------------------
extern "C" void kernel_launch(void* const* d_in, const int* in_sizes, int n_in,
                              void* d_out, int out_size, void* d_ws, size_t ws_size,
                              hipStream_t stream) {
    const float* resid = (const float*)d_in[0];
    const float* WQ = (const float*)d_in[1];
    const float* WK = (const float*)d_in[2];
    const float* WV = (const float*)d_in[3];
    const float* WO = (const float*)d_in[4];
    const float* bQ = (const float*)d_in[5];
    const float* bK = (const float*)d_in[6];
    const float* bV = (const float*)d_in[7];
    const float* bO = (const float*)d_in[8];
    float* out = (float*)d_out;
    char* ws = (char*)d_ws;

    float2* rope = (float2*)(ws);                        // 1 MB
    u16* xn   = (u16*)(ws + (1ll  << 20));               // 8 MB
    u16* Wt   = (u16*)(ws + (9ll  << 20));               // 24 MB  [3][16][128][2048]
    u16* Wot  = (u16*)(ws + (33ll << 20));               // 8 MB   [2048][2048]
    u16* qkv  = (u16*)(ws + (41ll << 20));               // 24 MB  [q][k][vT]
    u16* z    = (u16*)(ws + (65ll << 20));               // 8 MB   [16][2048][128]
    // flash partials OVERLAY rope/xn/Wt (dead after gemm_qkv; rewritten next call)
    u16* pO   = (u16*)(ws);                              // 18.9 MB (1152 x 64 x 128 bf16)
    float2* ml = (float2*)(ws + (20ll << 20));           // 0.6 MB

    rope_kernel<<<SEQ, 64, 0, stream>>>(rope);
    ln_kernel<<<SEQ, 256, 0, stream>>>(resid, xn);

    transpose_qkv<<<dim3(2, 32, 48), 256, 0, stream>>>(WQ, WK, WV, Wt);
    transpose_wo<<<dim3(32, 32, 1), 256, 0, stream>>>(WO, Wot);

    gemm_qkv<<<192, 512, 0, stream>>>(xn, Wt, bQ, bK, bV, rope, qkv);

    const u16* Qg = qkv;
    const u16* Kg = qkv + 1ll * NH * SEQ * DH;
    const u16* Vt = qkv + 2ll * NH * SEQ * DH;
    flash_kernel<<<dim3(NH, 80), 256, 0, stream>>>(Qg, Kg, Vt, z, pO, ml);
    merge_kernel<<<dim3(NH, 24), 256, 0, stream>>>(pO, ml, z);

    gemm_out<<<dim3(16, 16), 256, 0, stream>>>(z, Wot, bO, out);
}